// Round 5
// baseline (2572.608 us; speedup 1.0000x reference)
//
#include <hip/hip_runtime.h>
#include <hip/hip_bf16.h>
#include <math.h>

#define HID 192
#define NNODES 5184
#define NSTEPS 16

typedef float f32x4 __attribute__((ext_vector_type(4)));
typedef __bf16 bf16x8 __attribute__((ext_vector_type(8)));
typedef unsigned short ushort_t;
typedef ushort_t us8 __attribute__((ext_vector_type(8)));

__device__ __forceinline__ ushort_t f2bf(float f){
    __hip_bfloat16 h = __float2bfloat16(f);
    return __builtin_bit_cast(ushort_t, h);
}
__device__ __forceinline__ float bf2f(ushort_t u){
    return __uint_as_float(((unsigned)u) << 16);
}

// swizzled index helpers (bank-conflict-free fragment reads)
#define ABI(r,c) ((r)*384 + ((c) ^ (((r)&7)<<3)))   // bf16 buffer [81][384]
#define HBI(r,c) ((r)*192 + ((c) ^ (((r)&7)<<3)))   // bf16 buffer [81][192]

// load MFMA A-fragment (16x32 bf16) from a [81][192] bf16 LDS buffer (HBI swizzle)
__device__ __forceinline__ bf16x8 ldsfrag(const ushort_t* buf, int rt, int ks, int lane){
    int r = rt*16 + (lane & 15);
    int k0 = ks*32 + ((lane >> 4) << 3);
    if (r < 81) return *(const bf16x8*)&buf[HBI(r, k0)];
    us8 z = {0,0,0,0,0,0,0,0};
    return __builtin_bit_cast(bf16x8, z);
}
// pre-permuted weight fragment: array of [ct][nks][64][8]
__device__ __forceinline__ bf16x8 wfragN(const ushort_t* W, int ct, int nks, int ks, int lane){
    return *(const bf16x8*)&W[(size_t)(((ct*nks) + ks)*64 + lane)*8];
}

// ---------------------------------------------------------------------------
// fp32 tiled GEMM -- used once for Wfused = W_m2 @ W_ih^T
// ---------------------------------------------------------------------------
template <bool TRANSB>
__global__ __launch_bounds__(256)
void k_gemm(const float* __restrict__ A, const float* __restrict__ B,
            const float* __restrict__ bias, float biasScale,
            float* __restrict__ C, int N) {
    const int K = HID;
    __shared__ float As[64][17];
    __shared__ float Bs[16][65];
    int tid = threadIdx.x;
    int tx = tid & 15, ty = tid >> 4;
    int rowBase = blockIdx.x * 64;
    int colBase = blockIdx.y * 64;
    float acc[4][4] = {};
    for (int k0 = 0; k0 < K; k0 += 16) {
        {
            int r = tid >> 2, kk = (tid & 3) << 2;
            const float4 av = *(const float4*)&A[(size_t)(rowBase + r) * K + k0 + kk];
            As[r][kk + 0] = av.x; As[r][kk + 1] = av.y;
            As[r][kk + 2] = av.z; As[r][kk + 3] = av.w;
        }
        if (!TRANSB) {
            int kk = tid >> 4, j4 = (tid & 15) << 2;
            const float4 bv = *(const float4*)&B[(size_t)(k0 + kk) * N + colBase + j4];
            Bs[kk][j4 + 0] = bv.x; Bs[kk][j4 + 1] = bv.y;
            Bs[kk][j4 + 2] = bv.z; Bs[kk][j4 + 3] = bv.w;
        } else {
            int jj = tid >> 2, kk = (tid & 3) << 2;
            const float4 bv = *(const float4*)&B[(size_t)(colBase + jj) * K + k0 + kk];
            Bs[kk + 0][jj] = bv.x; Bs[kk + 1][jj] = bv.y;
            Bs[kk + 2][jj] = bv.z; Bs[kk + 3][jj] = bv.w;
        }
        __syncthreads();
#pragma unroll
        for (int kk = 0; kk < 16; kk++) {
            float a0 = As[ty*4+0][kk], a1 = As[ty*4+1][kk];
            float a2 = As[ty*4+2][kk], a3 = As[ty*4+3][kk];
            float b0 = Bs[kk][tx*4+0], b1 = Bs[kk][tx*4+1];
            float b2 = Bs[kk][tx*4+2], b3 = Bs[kk][tx*4+3];
            acc[0][0]+=a0*b0; acc[0][1]+=a0*b1; acc[0][2]+=a0*b2; acc[0][3]+=a0*b3;
            acc[1][0]+=a1*b0; acc[1][1]+=a1*b1; acc[1][2]+=a1*b2; acc[1][3]+=a1*b3;
            acc[2][0]+=a2*b0; acc[2][1]+=a2*b1; acc[2][2]+=a2*b2; acc[2][3]+=a2*b3;
            acc[3][0]+=a3*b0; acc[3][1]+=a3*b1; acc[3][2]+=a3*b2; acc[3][3]+=a3*b3;
        }
        __syncthreads();
    }
    float4 bb = make_float4(0.f,0.f,0.f,0.f);
    if (bias) {
        bb = *(const float4*)&bias[colBase + tx*4];
        bb.x*=biasScale; bb.y*=biasScale; bb.z*=biasScale; bb.w*=biasScale;
    }
#pragma unroll
    for (int i = 0; i < 4; i++) {
        int r = rowBase + ty*4 + i;
        float4 o;
        o.x=acc[i][0]+bb.x; o.y=acc[i][1]+bb.y; o.z=acc[i][2]+bb.z; o.w=acc[i][3]+bb.w;
        *(float4*)&C[(size_t)r * N + colBase + tx*4] = o;
    }
}

// ---------------------------------------------------------------------------
// prep: permute weights into MFMA B-fragment layouts (validated r2-r4).
// ---------------------------------------------------------------------------
__global__ void k_prep(const float* __restrict__ W_m1, const float* __restrict__ Wfused,
                       const float* __restrict__ W_hh, const float* __restrict__ W_out,
                       const float* __restrict__ W_ih, const float* __restrict__ b_m2,
                       const float* __restrict__ b_ih,
                       ushort_t* __restrict__ Wm1b, ushort_t* __restrict__ Wr,
                       ushort_t* __restrict__ Wz, ushort_t* __restrict__ Wni,
                       ushort_t* __restrict__ Wnh, ushort_t* __restrict__ Woutb,
                       float* __restrict__ bias_f) {
    int t = blockIdx.x * 256 + threadIdx.x;
    const int n0 = 73728;            // Wm1b
    const int n1 = n0 + 73728;       // Wr
    const int n2 = n1 + 73728;       // Wz
    const int n3 = n2 + 36864;       // Wni
    const int n4 = n3 + 36864;       // Wnh
    const int n5 = n4 + 3072;        // Woutb
    const int n6 = n5 + 576;         // bias_f
    if (t < n0) {
        int idx = t;
        int e = idx & 7, lane = (idx >> 3) & 63, cs = idx >> 9;
        int ct = cs / 6, ks = cs - ct*6;
        int k = ks*32 + ((lane>>4)<<3) + e, col = ct*16 + (lane & 15);
        float v = (col < 192) ? W_m1[k*192 + col] : W_m1[(192 + k)*192 + (col - 192)];
        Wm1b[idx] = f2bf(v);
    } else if (t < n1) {
        int idx = t - n0;
        int e = idx & 7, lane = (idx >> 3) & 63, cs = idx >> 9;
        int ct = cs / 12, ks = cs - ct*12;
        int k = ks*32 + ((lane>>4)<<3) + e, col = ct*16 + (lane & 15);
        float v = (k < 192) ? Wfused[k*576 + col] : W_hh[col*192 + (k - 192)];
        Wr[idx] = f2bf(v);
    } else if (t < n2) {
        int idx = t - n1;
        int e = idx & 7, lane = (idx >> 3) & 63, cs = idx >> 9;
        int ct = cs / 12, ks = cs - ct*12;
        int k = ks*32 + ((lane>>4)<<3) + e, col = ct*16 + (lane & 15);
        float v = (k < 192) ? Wfused[k*576 + 192 + col] : W_hh[(192 + col)*192 + (k - 192)];
        Wz[idx] = f2bf(v);
    } else if (t < n3) {
        int idx = t - n2;
        int e = idx & 7, lane = (idx >> 3) & 63, cs = idx >> 9;
        int ct = cs / 6, ks = cs - ct*6;
        int k = ks*32 + ((lane>>4)<<3) + e, col = ct*16 + (lane & 15);
        Wni[idx] = f2bf(Wfused[k*576 + 384 + col]);
    } else if (t < n4) {
        int idx = t - n3;
        int e = idx & 7, lane = (idx >> 3) & 63, cs = idx >> 9;
        int ct = cs / 6, ks = cs - ct*6;
        int k = ks*32 + ((lane>>4)<<3) + e, col = ct*16 + (lane & 15);
        Wnh[idx] = f2bf(W_hh[(384 + col)*192 + k]);
    } else if (t < n5) {
        int idx = t - n4;
        int e = idx & 7, lane = (idx >> 3) & 63, ks = idx >> 9;
        int k = ks*32 + ((lane>>4)<<3) + e, col = lane & 15;
        Woutb[idx] = (col < 9) ? f2bf(W_out[k*9 + col]) : (ushort_t)0;
    } else if (t < n6) {
        int n = t - n5;
        float s = 0.f;
        for (int m = 0; m < 192; m++) s += b_m2[m] * W_ih[n*192 + m];
        bias_f[n] = 20.f * s + b_ih[n];
    }
}

// ---------------------------------------------------------------------------
// Monolithic RRN kernel. LDS map (139872 B):
//   Rb    bf16 [81][192] @0       (relu-agg; x-staging overlay at h0)
//   AB    bf16 [81][384] @31104   (A|B proj; f32 h0-scratch overlay)
//   hb    bf16 [81][192] @93312   (h state)
//   spart float2[972]    @124416  (per-(row,ct) LN partials)
//   ssum/ssq f32         @132192/132576
//   bm1s/gns/bens        @132960/133728/134496
//   biasfs/bhhs f32[576] @135264/137568
// No register array lives across more than one barrier except hc (36 f32).
// ---------------------------------------------------------------------------
__global__ __launch_bounds__(512, 1)
void k_main(const float* __restrict__ x, const float* __restrict__ W_in,
            const float* __restrict__ b_in, const float* __restrict__ g_in,
            const float* __restrict__ be_in, const float* __restrict__ pos,
            const float* __restrict__ b_m1, const float* __restrict__ g_n,
            const float* __restrict__ be_n, const float* __restrict__ b_hh,
            const float* __restrict__ b_out,
            const ushort_t* __restrict__ Wm1b, const ushort_t* __restrict__ Wr,
            const ushort_t* __restrict__ Wz, const ushort_t* __restrict__ Wni,
            const ushort_t* __restrict__ Wnh, const ushort_t* __restrict__ Woutb,
            const float* __restrict__ bias_f,
            float* __restrict__ out_all, float* __restrict__ out_last)
{
    extern __shared__ char smem[];
    ushort_t* Rb    = (ushort_t*)(smem);
    ushort_t* AB    = (ushort_t*)(smem + 31104);
    ushort_t* hb    = (ushort_t*)(smem + 93312);
    float2*   spart = (float2*)(smem + 124416);
    float* ssum   = (float*)(smem + 132192);
    float* ssq    = (float*)(smem + 132576);
    float* bm1s   = (float*)(smem + 132960);
    float* gns    = (float*)(smem + 133728);
    float* bens   = (float*)(smem + 134496);
    float* biasfs = (float*)(smem + 135264);
    float* bhhs   = (float*)(smem + 137568);

    const int tid = threadIdx.x;
    const int lane = tid & 63, wave = tid >> 6;
    const int l15 = lane & 15, q4 = (lane >> 4) << 2;
    const int g = blockIdx.x;

    if (tid < 192) { bm1s[tid] = b_m1[tid]; gns[tid] = g_n[tid]; bens[tid] = be_n[tid]; }
    for (int e = tid; e < 576; e += 512) { biasfs[e] = bias_f[e]; bhhs[e] = b_hh[e]; }

    // ---------------- h0 = LN(x@W_in + b_in)*g+be + pos ----------------
    {
        float* xs = (float*)Rb;           // x staging (3240 B)
        float* vf = (float*)AB;           // f32 scratch [81][192] linear (62208 B)
        for (int e = tid; e < 810; e += 512) xs[e] = x[(size_t)g*810 + e];
        __syncthreads();
        for (int e = tid; e < 15552; e += 512) {
            int n = e / 192, j = e - n*192;
            float v = b_in[j];
#pragma unroll
            for (int k = 0; k < 10; k++) v += xs[n*10 + k] * W_in[k*192 + j];
            vf[n*192 + j] = v;
        }
        __syncthreads();
        if (tid < 324) {
            int row = tid >> 2, part = tid & 3;
            float s = 0.f, q = 0.f;
#pragma unroll
            for (int i = 0; i < 12; i++) {
                float4 v = *(float4*)&vf[row*192 + part*48 + i*4];
                s += v.x + v.y + v.z + v.w;
                q += v.x*v.x + v.y*v.y + v.z*v.z + v.w*v.w;
            }
            spart[tid] = make_float2(s, q);
        }
        __syncthreads();
        if (tid < 81) {
            float2 p0 = spart[tid*4], p1 = spart[tid*4+1], p2 = spart[tid*4+2], p3 = spart[tid*4+3];
            float s = p0.x+p1.x+p2.x+p3.x, q = p0.y+p1.y+p2.y+p3.y;
            float m = s * (1.f/192.f);
            float var = q * (1.f/192.f) - m*m;
            ssum[tid] = m; ssq[tid] = rsqrtf(var + 1e-5f);
        }
        __syncthreads();
        for (int e = tid; e < 15552; e += 512) {
            int n = e / 192, j = e - n*192;
            float v = vf[n*192 + j];
            v = (v - ssum[n]) * ssq[n] * g_in[j] + be_in[j] + pos[n*192 + j];
            hb[HBI(n, j)] = f2bf(v);
        }
        __syncthreads();
    }

    for (int t = 0; t < NSTEPS; t++) {
        // ===== Phase A: [A|B] = h @ Wm1comb (b_m1 folded into B half) =====
#pragma unroll
        for (int c = 0; c < 3; c++) {
            bf16x8 wbc[6];
#pragma unroll
            for (int ks = 0; ks < 6; ks++)
                wbc[ks] = wfragN(Wm1b, wave*3 + c, 6, ks, lane);
            int col = (wave*3 + c)*16 + l15;
            float addb = (col >= 192) ? bm1s[col - 192] : 0.f;
#pragma unroll
            for (int rt = 0; rt < 6; rt++) {
                f32x4 acc = {0.f, 0.f, 0.f, 0.f};
#pragma unroll
                for (int ks = 0; ks < 6; ks++)
                    acc = __builtin_amdgcn_mfma_f32_16x16x32_bf16(ldsfrag(hb, rt, ks, lane), wbc[ks], acc, 0, 0, 0);
#pragma unroll
                for (int i2 = 0; i2 < 4; i2++) {
                    int row = rt*16 + q4 + i2;
                    if (row < 81) AB[ABI(row, col)] = f2bf(acc[i2] + addb);
                }
            }
        }
        __syncthreads();   // SYNC_A

        // ===== Phase B: Rb[d] = sum_{s in nbr(d)} relu(A[s] + B[d]) =====
        // reads AB, writes Rb immediately (no cross-barrier registers)
#pragma unroll
        for (int it = 0; it < 4; it++) {
            int e = tid + 512*it;
            if (e < 1944) {
                int d = e / 24, j8 = e - d*24;
                int j0 = j8 * 8;
                float bsum[8], r8[8] = {0,0,0,0,0,0,0,0};
                us8 bu = *(const us8*)&AB[ABI(d, 192 + j0)];
#pragma unroll
                for (int i = 0; i < 8; i++) bsum[i] = bf2f(bu[i]);
                int rr = d / 9, cc = d - rr*9;
                int rb0 = (rr/3)*3, cb0 = (cc/3)*3;
#pragma unroll
                for (int c2 = 0; c2 < 9; c2++) {
                    if (c2 == cc) continue;
                    us8 au = *(const us8*)&AB[ABI(rr*9 + c2, j0)];
#pragma unroll
                    for (int i = 0; i < 8; i++) r8[i] += fmaxf(bf2f(au[i]) + bsum[i], 0.f);
                }
#pragma unroll
                for (int r2 = 0; r2 < 9; r2++) {
                    if (r2 == rr) continue;
                    us8 au = *(const us8*)&AB[ABI(r2*9 + cc, j0)];
#pragma unroll
                    for (int i = 0; i < 8; i++) r8[i] += fmaxf(bf2f(au[i]) + bsum[i], 0.f);
                }
#pragma unroll
                for (int r2 = 0; r2 < 3; r2++) {
                    int rrr = rb0 + r2;
                    if (rrr == rr) continue;
#pragma unroll
                    for (int c2 = 0; c2 < 3; c2++) {
                        int ccc = cb0 + c2;
                        if (ccc == cc) continue;
                        us8 au = *(const us8*)&AB[ABI(rrr*9 + ccc, j0)];
#pragma unroll
                        for (int i = 0; i < 8; i++) r8[i] += fmaxf(bf2f(au[i]) + bsum[i], 0.f);
                    }
                }
                us8 w;
#pragma unroll
                for (int i = 0; i < 8; i++) w[i] = f2bf(r8[i]);
                *(us8*)&Rb[HBI(d, j0)] = w;
            }
        }
        __syncthreads();   // SYNC_B

        // ===== Phase C: 24 units (12 col-tiles x 2 row-halves), 3/wave =====
        // gates via 2 passes; hc kept in registers across LN-stats barrier
        float hc[3][3][4];
#pragma unroll
        for (int uu = 0; uu < 3; uu++) {
            int u = wave + uu*8;
            int ct = (u < 12) ? u : (u - 12);
            int rh = (u < 12) ? 0 : 1;
            int col = ct*16 + l15;
            // pass 1: r,z gates over K=384 ([Rb | hb])
            f32x4 ar[3] = {}, az[3] = {};
#pragma unroll
            for (int ks = 0; ks < 12; ks++) {
                bf16x8 wfr = wfragN(Wr, ct, 12, ks, lane);
                bf16x8 wfz = wfragN(Wz, ct, 12, ks, lane);
#pragma unroll
                for (int r3 = 0; r3 < 3; r3++) {
                    int rt = rh*3 + r3;
                    bf16x8 af = (ks < 6) ? ldsfrag(Rb, rt, ks, lane)
                                         : ldsfrag(hb, rt, ks - 6, lane);
                    ar[r3] = __builtin_amdgcn_mfma_f32_16x16x32_bf16(af, wfr, ar[r3], 0,0,0);
                    az[r3] = __builtin_amdgcn_mfma_f32_16x16x32_bf16(af, wfz, az[r3], 0,0,0);
                }
            }
            // pass 2: n gate (inn over Rb, hn over hb)
            f32x4 ani[3] = {}, anh[3] = {};
#pragma unroll
            for (int ks = 0; ks < 6; ks++) {
                bf16x8 wni = wfragN(Wni, ct, 6, ks, lane);
                bf16x8 wnh = wfragN(Wnh, ct, 6, ks, lane);
#pragma unroll
                for (int r3 = 0; r3 < 3; r3++) {
                    int rt = rh*3 + r3;
                    ani[r3] = __builtin_amdgcn_mfma_f32_16x16x32_bf16(ldsfrag(Rb, rt, ks, lane), wni, ani[r3], 0,0,0);
                    anh[r3] = __builtin_amdgcn_mfma_f32_16x16x32_bf16(ldsfrag(hb, rt, ks, lane), wnh, anh[r3], 0,0,0);
                }
            }
            float br  = biasfs[col]       + bhhs[col];
            float bz  = biasfs[col + 192] + bhhs[col + 192];
            float bni = biasfs[col + 384];
            float bnh = bhhs[col + 384];
#pragma unroll
            for (int r3 = 0; r3 < 3; r3++) {
#pragma unroll
                for (int i2 = 0; i2 < 4; i2++) {
                    int row = (rh*3 + r3)*16 + q4 + i2;
                    float hv = (row < 81) ? bf2f(hb[HBI(row, col)]) : 0.f;
                    float rg = 1.f/(1.f + __expf(-(ar[r3][i2] + br)));
                    float zg = 1.f/(1.f + __expf(-(az[r3][i2] + bz)));
                    float e2 = __expf(2.f*(ani[r3][i2] + bni + rg*(anh[r3][i2] + bnh)));
                    float ng = 1.f - 2.f/(e2 + 1.f);
                    float v = (1.f - zg)*ng + zg*hv;
                    hc[uu][r3][i2] = v;
                    // per-(row,ct) partial sums across the 16 cols (lanes)
                    float s = v, q = v*v;
#pragma unroll
                    for (int m = 1; m < 16; m <<= 1) {
                        s += __shfl_xor(s, m);
                        q += __shfl_xor(q, m);
                    }
                    if (l15 == 0 && row < 81) spart[row*12 + ct] = make_float2(s, q);
                }
            }
        }
        __syncthreads();   // SYNC_C

        // ===== LN stats =====
        if (tid < 81) {
            float s = 0.f, q = 0.f;
#pragma unroll
            for (int i = 0; i < 12; i++) {
                float2 p = spart[tid*12 + i];
                s += p.x; q += p.y;
            }
            float m = s * (1.f/192.f);
            float var = q * (1.f/192.f) - m*m;
            ssum[tid] = m; ssq[tid] = rsqrtf(var + 1e-5f);
        }
        __syncthreads();   // SYNC_S

        // ===== write hb = LN(hc) from registers =====
#pragma unroll
        for (int uu = 0; uu < 3; uu++) {
            int u = wave + uu*8;
            int ct = (u < 12) ? u : (u - 12);
            int rh = (u < 12) ? 0 : 1;
            int col = ct*16 + l15;
            float gj = gns[col], bj = bens[col];
#pragma unroll
            for (int r3 = 0; r3 < 3; r3++) {
#pragma unroll
                for (int i2 = 0; i2 < 4; i2++) {
                    int row = (rh*3 + r3)*16 + q4 + i2;
                    if (row < 81) {
                        float v = (hc[uu][r3][i2] - ssum[row]) * ssq[row] * gj + bj;
                        hb[HBI(row, col)] = f2bf(v);
                    }
                }
            }
        }
        __syncthreads();   // SYNC_H

        // ===== Phase E: logits = h @ W_out + b_out (waves 0-5) =====
        if (wave < 6) {
            int rt = wave;
            f32x4 acc = {0.f, 0.f, 0.f, 0.f};
#pragma unroll
            for (int ks = 0; ks < 6; ks++) {
                bf16x8 ha = ldsfrag(hb, rt, ks, lane);
                acc = __builtin_amdgcn_mfma_f32_16x16x32_bf16(ha, wfragN(Woutb, 0, 6, ks, lane), acc, 0,0,0);
            }
            if (l15 < 9) {
                float bo = b_out[l15];
#pragma unroll
                for (int i2 = 0; i2 < 4; i2++) {
                    int row = rt*16 + q4 + i2;
                    if (row < 81) {
                        float v = acc[i2] + bo;
                        out_all[((size_t)t*NNODES + (size_t)g*81 + row)*9 + l15] = v;
                        if (t == NSTEPS-1)
                            out_last[((size_t)g*81 + row)*9 + l15] = v;
                    }
                }
            }
        }
    }
}

// ---------------------------------------------------------------------------
extern "C" void kernel_launch(void* const* d_in, const int* in_sizes, int n_in,
                              void* d_out, int out_size, void* d_ws, size_t ws_size,
                              hipStream_t stream) {
    const float* x     = (const float*)d_in[0];
    const float* W_in  = (const float*)d_in[2];
    const float* b_in  = (const float*)d_in[3];
    const float* g_in  = (const float*)d_in[4];
    const float* be_in = (const float*)d_in[5];
    const float* pos   = (const float*)d_in[6];
    const float* W_m1  = (const float*)d_in[7];
    const float* b_m1  = (const float*)d_in[8];
    const float* W_m2  = (const float*)d_in[9];
    const float* b_m2  = (const float*)d_in[10];
    const float* W_ih  = (const float*)d_in[11];
    const float* W_hh  = (const float*)d_in[12];
    const float* b_ih  = (const float*)d_in[13];
    const float* b_hh  = (const float*)d_in[14];
    const float* g_n   = (const float*)d_in[15];
    const float* be_n  = (const float*)d_in[16];
    const float* W_out = (const float*)d_in[17];
    const float* b_out = (const float*)d_in[18];

    char* ws = (char*)d_ws;
    float*    Wfused = (float*)ws;                   // 442368
    ushort_t* Wm1b   = (ushort_t*)(ws + 442368);     // 147456
    ushort_t* Wr     = (ushort_t*)(ws + 589824);     // 147456
    ushort_t* Wz     = (ushort_t*)(ws + 737280);     // 147456
    ushort_t* Wni    = (ushort_t*)(ws + 884736);     // 73728
    ushort_t* Wnh    = (ushort_t*)(ws + 958464);     // 73728
    ushort_t* Woutb  = (ushort_t*)(ws + 1032192);    // 6144
    float*    bias_f = (float*)(ws + 1038336);       // 2304

    float* out_last = (float*)d_out;                 // (5184, 9)
    float* out_all  = (float*)d_out + NNODES*9;      // (16, 5184, 9)

    // Wfused = W_m2 @ W_ih^T   (192 x 576, fp32)
    k_gemm<true><<<dim3(3, 9), 256, 0, stream>>>(W_m2, W_ih, nullptr, 0.f, Wfused, 576);
    // weight -> bf16 fragment layouts + fused bias
    k_prep<<<(298560 + 255)/256, 256, 0, stream>>>(W_m1, Wfused, W_hh, W_out, W_ih, b_m2, b_ih,
                                                   Wm1b, Wr, Wz, Wni, Wnh, Woutb, bias_f);

    const int LDS_BYTES = 139872;
    hipFuncSetAttribute(reinterpret_cast<const void*>(k_main),
                        hipFuncAttributeMaxDynamicSharedMemorySize, LDS_BYTES);
    k_main<<<64, 512, LDS_BYTES, stream>>>(x, W_in, b_in, g_in, be_in, pos, b_m1, g_n, be_n,
                                           b_hh, b_out, Wm1b, Wr, Wz, Wni, Wnh, Woutb, bias_f,
                                           out_all, out_last);
}

// Round 6
// 2437.608 us; speedup vs baseline: 1.0554x; 1.0554x over previous
//
#include <hip/hip_runtime.h>
#include <hip/hip_bf16.h>
#include <math.h>

#define HID 192
#define NNODES 5184
#define NSTEPS 16

typedef float f32x4 __attribute__((ext_vector_type(4)));
typedef __bf16 bf16x8 __attribute__((ext_vector_type(8)));
typedef unsigned short ushort_t;
typedef ushort_t us8 __attribute__((ext_vector_type(8)));

__device__ __forceinline__ ushort_t f2bf(float f){
    __hip_bfloat16 h = __float2bfloat16(f);
    return __builtin_bit_cast(ushort_t, h);
}
__device__ __forceinline__ float bf2f(ushort_t u){
    return __uint_as_float(((unsigned)u) << 16);
}

// swizzled index helpers (bank-conflict-free fragment reads)
#define HFI(r,c) ((r)*192 + ((c) ^ (((r)&7)<<2)))   // f32 buffer [81][192]
#define ABI(r,c) ((r)*384 + ((c) ^ (((r)&7)<<3)))   // bf16 buffer [81][384]
#define HBI(r,c) ((r)*192 + ((c) ^ (((r)&7)<<3)))   // bf16 buffer [81][192]

// load MFMA A-fragment (16x32 bf16) from a [81][192] bf16 LDS buffer (HBI swizzle)
__device__ __forceinline__ bf16x8 ldsfrag(const ushort_t* buf, int rt, int ks, int lane){
    int r = rt*16 + (lane & 15);
    int k0 = ks*32 + ((lane >> 4) << 3);
    if (r < 81) return *(const bf16x8*)&buf[HBI(r, k0)];
    us8 z = {0,0,0,0,0,0,0,0};
    return __builtin_bit_cast(bf16x8, z);
}
// pre-permuted weight fragment: array of [ct][nks][64][8]
__device__ __forceinline__ bf16x8 wfragN(const ushort_t* W, int ct, int nks, int ks, int lane){
    return *(const bf16x8*)&W[(size_t)(((ct*nks) + ks)*64 + lane)*8];
}

// ---------------------------------------------------------------------------
// fp32 tiled GEMM -- used once for Wfused = W_m2 @ W_ih^T
// ---------------------------------------------------------------------------
template <bool TRANSB>
__global__ __launch_bounds__(256)
void k_gemm(const float* __restrict__ A, const float* __restrict__ B,
            const float* __restrict__ bias, float biasScale,
            float* __restrict__ C, int N) {
    const int K = HID;
    __shared__ float As[64][17];
    __shared__ float Bs[16][65];
    int tid = threadIdx.x;
    int tx = tid & 15, ty = tid >> 4;
    int rowBase = blockIdx.x * 64;
    int colBase = blockIdx.y * 64;
    float acc[4][4] = {};
    for (int k0 = 0; k0 < K; k0 += 16) {
        {
            int r = tid >> 2, kk = (tid & 3) << 2;
            const float4 av = *(const float4*)&A[(size_t)(rowBase + r) * K + k0 + kk];
            As[r][kk + 0] = av.x; As[r][kk + 1] = av.y;
            As[r][kk + 2] = av.z; As[r][kk + 3] = av.w;
        }
        if (!TRANSB) {
            int kk = tid >> 4, j4 = (tid & 15) << 2;
            const float4 bv = *(const float4*)&B[(size_t)(k0 + kk) * N + colBase + j4];
            Bs[kk][j4 + 0] = bv.x; Bs[kk][j4 + 1] = bv.y;
            Bs[kk][j4 + 2] = bv.z; Bs[kk][j4 + 3] = bv.w;
        } else {
            int jj = tid >> 2, kk = (tid & 3) << 2;
            const float4 bv = *(const float4*)&B[(size_t)(colBase + jj) * K + k0 + kk];
            Bs[kk + 0][jj] = bv.x; Bs[kk + 1][jj] = bv.y;
            Bs[kk + 2][jj] = bv.z; Bs[kk + 3][jj] = bv.w;
        }
        __syncthreads();
#pragma unroll
        for (int kk = 0; kk < 16; kk++) {
            float a0 = As[ty*4+0][kk], a1 = As[ty*4+1][kk];
            float a2 = As[ty*4+2][kk], a3 = As[ty*4+3][kk];
            float b0 = Bs[kk][tx*4+0], b1 = Bs[kk][tx*4+1];
            float b2 = Bs[kk][tx*4+2], b3 = Bs[kk][tx*4+3];
            acc[0][0]+=a0*b0; acc[0][1]+=a0*b1; acc[0][2]+=a0*b2; acc[0][3]+=a0*b3;
            acc[1][0]+=a1*b0; acc[1][1]+=a1*b1; acc[1][2]+=a1*b2; acc[1][3]+=a1*b3;
            acc[2][0]+=a2*b0; acc[2][1]+=a2*b1; acc[2][2]+=a2*b2; acc[2][3]+=a2*b3;
            acc[3][0]+=a3*b0; acc[3][1]+=a3*b1; acc[3][2]+=a3*b2; acc[3][3]+=a3*b3;
        }
        __syncthreads();
    }
    float4 bb = make_float4(0.f,0.f,0.f,0.f);
    if (bias) {
        bb = *(const float4*)&bias[colBase + tx*4];
        bb.x*=biasScale; bb.y*=biasScale; bb.z*=biasScale; bb.w*=biasScale;
    }
#pragma unroll
    for (int i = 0; i < 4; i++) {
        int r = rowBase + ty*4 + i;
        float4 o;
        o.x=acc[i][0]+bb.x; o.y=acc[i][1]+bb.y; o.z=acc[i][2]+bb.z; o.w=acc[i][3]+bb.w;
        *(float4*)&C[(size_t)r * N + colBase + tx*4] = o;
    }
}

// ---------------------------------------------------------------------------
// prep: permute weights into MFMA B-fragment layouts (validated r2-r5).
// ---------------------------------------------------------------------------
__global__ void k_prep(const float* __restrict__ W_m1, const float* __restrict__ Wfused,
                       const float* __restrict__ W_hh, const float* __restrict__ W_out,
                       const float* __restrict__ W_ih, const float* __restrict__ b_m2,
                       const float* __restrict__ b_ih,
                       ushort_t* __restrict__ Wm1b, ushort_t* __restrict__ Wr,
                       ushort_t* __restrict__ Wz, ushort_t* __restrict__ Wni,
                       ushort_t* __restrict__ Wnh, ushort_t* __restrict__ Woutb,
                       float* __restrict__ bias_f) {
    int t = blockIdx.x * 256 + threadIdx.x;
    const int n0 = 73728;            // Wm1b
    const int n1 = n0 + 73728;       // Wr
    const int n2 = n1 + 73728;       // Wz
    const int n3 = n2 + 36864;       // Wni
    const int n4 = n3 + 36864;       // Wnh
    const int n5 = n4 + 3072;        // Woutb
    const int n6 = n5 + 576;         // bias_f
    if (t < n0) {
        int idx = t;
        int e = idx & 7, lane = (idx >> 3) & 63, cs = idx >> 9;
        int ct = cs / 6, ks = cs - ct*6;
        int k = ks*32 + ((lane>>4)<<3) + e, col = ct*16 + (lane & 15);
        float v = (col < 192) ? W_m1[k*192 + col] : W_m1[(192 + k)*192 + (col - 192)];
        Wm1b[idx] = f2bf(v);
    } else if (t < n1) {
        int idx = t - n0;
        int e = idx & 7, lane = (idx >> 3) & 63, cs = idx >> 9;
        int ct = cs / 12, ks = cs - ct*12;
        int k = ks*32 + ((lane>>4)<<3) + e, col = ct*16 + (lane & 15);
        float v = (k < 192) ? Wfused[k*576 + col] : W_hh[col*192 + (k - 192)];
        Wr[idx] = f2bf(v);
    } else if (t < n2) {
        int idx = t - n1;
        int e = idx & 7, lane = (idx >> 3) & 63, cs = idx >> 9;
        int ct = cs / 12, ks = cs - ct*12;
        int k = ks*32 + ((lane>>4)<<3) + e, col = ct*16 + (lane & 15);
        float v = (k < 192) ? Wfused[k*576 + 192 + col] : W_hh[(192 + col)*192 + (k - 192)];
        Wz[idx] = f2bf(v);
    } else if (t < n3) {
        int idx = t - n2;
        int e = idx & 7, lane = (idx >> 3) & 63, cs = idx >> 9;
        int ct = cs / 6, ks = cs - ct*6;
        int k = ks*32 + ((lane>>4)<<3) + e, col = ct*16 + (lane & 15);
        Wni[idx] = f2bf(Wfused[k*576 + 384 + col]);
    } else if (t < n4) {
        int idx = t - n3;
        int e = idx & 7, lane = (idx >> 3) & 63, cs = idx >> 9;
        int ct = cs / 6, ks = cs - ct*6;
        int k = ks*32 + ((lane>>4)<<3) + e, col = ct*16 + (lane & 15);
        Wnh[idx] = f2bf(W_hh[(384 + col)*192 + k]);
    } else if (t < n5) {
        int idx = t - n4;
        int e = idx & 7, lane = (idx >> 3) & 63, ks = idx >> 9;
        int k = ks*32 + ((lane>>4)<<3) + e, col = lane & 15;
        Woutb[idx] = (col < 9) ? f2bf(W_out[k*9 + col]) : (ushort_t)0;
    } else if (t < n6) {
        int n = t - n5;
        float s = 0.f;
        for (int m = 0; m < 192; m++) s += b_m2[m] * W_ih[n*192 + m];
        bias_f[n] = 20.f * s + b_ih[n];
    }
}

// ---------------------------------------------------------------------------
// Monolithic RRN kernel. LDS map (134568 B):
//   Rb    bf16 [81][192] @0       (relu-agg; x-staging overlay at h0)
//   AB    bf16 [81][384] @31104   (A|B proj)  -- hcf f32 [81][192] OVERLAYS
//         this region (AB dead after Phase B; hcf live Phase C -> Phase D)
//   hb    bf16 [81][192] @93312   (h state)
//   spart float2[324]    @124416  (LN partials)
//   ssum/ssq f32[81]     @127008/127332
//   bm1s/gns/bens f32[192] @127656/128424/129192
//   biasfs/bhhs f32[576] @129960/132264
// RULE: no register array is live across any __syncthreads().
// ---------------------------------------------------------------------------
__global__ __launch_bounds__(512)
void k_main(const float* __restrict__ x, const float* __restrict__ W_in,
            const float* __restrict__ b_in, const float* __restrict__ g_in,
            const float* __restrict__ be_in, const float* __restrict__ pos,
            const float* __restrict__ b_m1, const float* __restrict__ g_n,
            const float* __restrict__ be_n, const float* __restrict__ b_hh,
            const float* __restrict__ b_out,
            const ushort_t* __restrict__ Wm1b, const ushort_t* __restrict__ Wr,
            const ushort_t* __restrict__ Wz, const ushort_t* __restrict__ Wni,
            const ushort_t* __restrict__ Wnh, const ushort_t* __restrict__ Woutb,
            const float* __restrict__ bias_f,
            float* __restrict__ out_all, float* __restrict__ out_last)
{
    extern __shared__ char smem[];
    ushort_t* Rb    = (ushort_t*)(smem);
    ushort_t* AB    = (ushort_t*)(smem + 31104);
    float*    hcf   = (float*)(smem + 31104);        // overlays AB
    ushort_t* hb    = (ushort_t*)(smem + 93312);
    float2*   spart = (float2*)(smem + 124416);
    float* ssum   = (float*)(smem + 127008);
    float* ssq    = (float*)(smem + 127332);
    float* bm1s   = (float*)(smem + 127656);
    float* gns    = (float*)(smem + 128424);
    float* bens   = (float*)(smem + 129192);
    float* biasfs = (float*)(smem + 129960);
    float* bhhs   = (float*)(smem + 132264);

    const int tid = threadIdx.x;
    const int lane = tid & 63, wave = tid >> 6;
    const int l15 = lane & 15, q4 = (lane >> 4) << 2;
    const int g = blockIdx.x;

    if (tid < 192) { bm1s[tid] = b_m1[tid]; gns[tid] = g_n[tid]; bens[tid] = be_n[tid]; }
    for (int e = tid; e < 576; e += 512) { biasfs[e] = bias_f[e]; bhhs[e] = b_hh[e]; }

    // ---------------- h0 = LN(x@W_in + b_in)*g+be + pos ----------------
    {
        float* xs = (float*)Rb;           // x staging (3240 B)
        float* vf = hcf;                  // f32 scratch [81][192] linear
        for (int e = tid; e < 810; e += 512) xs[e] = x[(size_t)g*810 + e];
        __syncthreads();
        for (int e = tid; e < 15552; e += 512) {
            int n = e / 192, j = e - n*192;
            float v = b_in[j];
#pragma unroll
            for (int k = 0; k < 10; k++) v += xs[n*10 + k] * W_in[k*192 + j];
            vf[n*192 + j] = v;
        }
        __syncthreads();
        if (tid < 324) {
            int row = tid >> 2, part = tid & 3;
            float s = 0.f, q = 0.f;
#pragma unroll
            for (int i = 0; i < 12; i++) {
                float4 v = *(float4*)&vf[row*192 + part*48 + i*4];
                s += v.x + v.y + v.z + v.w;
                q += v.x*v.x + v.y*v.y + v.z*v.z + v.w*v.w;
            }
            spart[tid] = make_float2(s, q);
        }
        __syncthreads();
        if (tid < 81) {
            float2 p0 = spart[tid*4], p1 = spart[tid*4+1], p2 = spart[tid*4+2], p3 = spart[tid*4+3];
            float s = p0.x+p1.x+p2.x+p3.x, q = p0.y+p1.y+p2.y+p3.y;
            float m = s * (1.f/192.f);
            float var = q * (1.f/192.f) - m*m;
            ssum[tid] = m; ssq[tid] = rsqrtf(var + 1e-5f);
        }
        __syncthreads();
        for (int e = tid; e < 15552; e += 512) {
            int n = e / 192, j = e - n*192;
            float v = vf[n*192 + j];
            v = (v - ssum[n]) * ssq[n] * g_in[j] + be_in[j] + pos[n*192 + j];
            hb[HBI(n, j)] = f2bf(v);
        }
        __syncthreads();
    }

    for (int t = 0; t < NSTEPS; t++) {
        // ===== Phase A: [A|B] = h @ Wm1comb (b_m1 folded into B half) =====
#pragma unroll
        for (int c = 0; c < 3; c++) {
            bf16x8 wbc[6];
#pragma unroll
            for (int ks = 0; ks < 6; ks++)
                wbc[ks] = wfragN(Wm1b, wave*3 + c, 6, ks, lane);
            int col = (wave*3 + c)*16 + l15;
            float addb = (col >= 192) ? bm1s[col - 192] : 0.f;
#pragma unroll
            for (int rt = 0; rt < 6; rt++) {
                f32x4 acc = {0.f, 0.f, 0.f, 0.f};
#pragma unroll
                for (int ks = 0; ks < 6; ks++)
                    acc = __builtin_amdgcn_mfma_f32_16x16x32_bf16(ldsfrag(hb, rt, ks, lane), wbc[ks], acc, 0, 0, 0);
#pragma unroll
                for (int i2 = 0; i2 < 4; i2++) {
                    int row = rt*16 + q4 + i2;
                    if (row < 81) AB[ABI(row, col)] = f2bf(acc[i2] + addb);
                }
            }
        }
        __syncthreads();   // SYNC_A

        // ===== Phase B: Rb[d] = sum_{s in nbr(d)} relu(A[s] + B[d]) =====
        // reads AB, writes Rb immediately (no cross-barrier registers)
#pragma unroll
        for (int it = 0; it < 4; it++) {
            int e = tid + 512*it;
            if (e < 1944) {
                int d = e / 24, j8 = e - d*24;
                int j0 = j8 * 8;
                float bsum[8], r8[8] = {0,0,0,0,0,0,0,0};
                us8 bu = *(const us8*)&AB[ABI(d, 192 + j0)];
#pragma unroll
                for (int i = 0; i < 8; i++) bsum[i] = bf2f(bu[i]);
                int rr = d / 9, cc = d - rr*9;
                int rb0 = (rr/3)*3, cb0 = (cc/3)*3;
#pragma unroll
                for (int c2 = 0; c2 < 9; c2++) {
                    if (c2 == cc) continue;
                    us8 au = *(const us8*)&AB[ABI(rr*9 + c2, j0)];
#pragma unroll
                    for (int i = 0; i < 8; i++) r8[i] += fmaxf(bf2f(au[i]) + bsum[i], 0.f);
                }
#pragma unroll
                for (int r2 = 0; r2 < 9; r2++) {
                    if (r2 == rr) continue;
                    us8 au = *(const us8*)&AB[ABI(r2*9 + cc, j0)];
#pragma unroll
                    for (int i = 0; i < 8; i++) r8[i] += fmaxf(bf2f(au[i]) + bsum[i], 0.f);
                }
#pragma unroll
                for (int r2 = 0; r2 < 3; r2++) {
                    int rrr = rb0 + r2;
                    if (rrr == rr) continue;
#pragma unroll
                    for (int c2 = 0; c2 < 3; c2++) {
                        int ccc = cb0 + c2;
                        if (ccc == cc) continue;
                        us8 au = *(const us8*)&AB[ABI(rrr*9 + ccc, j0)];
#pragma unroll
                        for (int i = 0; i < 8; i++) r8[i] += fmaxf(bf2f(au[i]) + bsum[i], 0.f);
                    }
                }
                us8 w;
#pragma unroll
                for (int i = 0; i < 8; i++) w[i] = f2bf(r8[i]);
                *(us8*)&Rb[HBI(d, j0)] = w;
            }
        }
        __syncthreads();   // SYNC_B
        // NOTE: AB is dead from here; hcf overlays it.

        // ===== Phase C: 24 units (12 col-tiles x 2 row-halves), 3/wave =====
        // two passes to cap accumulator liveness; hc -> hcf (LDS), not regs
#pragma unroll
        for (int uu = 0; uu < 3; uu++) {
            int u = wave + uu*8;
            int ct = (u < 12) ? u : (u - 12);
            int rh = (u < 12) ? 0 : 1;
            int col = ct*16 + l15;
            // pass 1: r,z gates over K=384 ([Rb | hb])
            f32x4 ar[3] = {}, az[3] = {};
#pragma unroll
            for (int ks = 0; ks < 12; ks++) {
                bf16x8 wfr = wfragN(Wr, ct, 12, ks, lane);
                bf16x8 wfz = wfragN(Wz, ct, 12, ks, lane);
#pragma unroll
                for (int r3 = 0; r3 < 3; r3++) {
                    int rt = rh*3 + r3;
                    bf16x8 af = (ks < 6) ? ldsfrag(Rb, rt, ks, lane)
                                         : ldsfrag(hb, rt, ks - 6, lane);
                    ar[r3] = __builtin_amdgcn_mfma_f32_16x16x32_bf16(af, wfr, ar[r3], 0,0,0);
                    az[r3] = __builtin_amdgcn_mfma_f32_16x16x32_bf16(af, wfz, az[r3], 0,0,0);
                }
            }
            // pass 2: n gate (inn over Rb, hn over hb)
            f32x4 ani[3] = {}, anh[3] = {};
#pragma unroll
            for (int ks = 0; ks < 6; ks++) {
                bf16x8 wni = wfragN(Wni, ct, 6, ks, lane);
                bf16x8 wnh = wfragN(Wnh, ct, 6, ks, lane);
#pragma unroll
                for (int r3 = 0; r3 < 3; r3++) {
                    int rt = rh*3 + r3;
                    ani[r3] = __builtin_amdgcn_mfma_f32_16x16x32_bf16(ldsfrag(Rb, rt, ks, lane), wni, ani[r3], 0,0,0);
                    anh[r3] = __builtin_amdgcn_mfma_f32_16x16x32_bf16(ldsfrag(hb, rt, ks, lane), wnh, anh[r3], 0,0,0);
                }
            }
            float br  = biasfs[col]       + bhhs[col];
            float bz  = biasfs[col + 192] + bhhs[col + 192];
            float bni = biasfs[col + 384];
            float bnh = bhhs[col + 384];
#pragma unroll
            for (int r3 = 0; r3 < 3; r3++) {
#pragma unroll
                for (int i2 = 0; i2 < 4; i2++) {
                    int row = (rh*3 + r3)*16 + q4 + i2;
                    if (row < 81) {
                        float hv = bf2f(hb[HBI(row, col)]);
                        float rg = 1.f/(1.f + __expf(-(ar[r3][i2] + br)));
                        float zg = 1.f/(1.f + __expf(-(az[r3][i2] + bz)));
                        float e2 = __expf(2.f*(ani[r3][i2] + bni + rg*(anh[r3][i2] + bnh)));
                        float ng = 1.f - 2.f/(e2 + 1.f);
                        hcf[HFI(row, col)] = (1.f - zg)*ng + zg*hv;
                    }
                }
            }
        }
        __syncthreads();   // SYNC_C

        // ===== LN stats (324-thread partial pass over hcf) =====
        if (tid < 324) {
            int row = tid >> 2, part = tid & 3;
            float s = 0.f, q = 0.f;
#pragma unroll
            for (int i = 0; i < 12; i++) {
                float4 v = *(float4*)&hcf[HFI(row, part*48 + i*4)];
                s += v.x + v.y + v.z + v.w;
                q += v.x*v.x + v.y*v.y + v.z*v.z + v.w*v.w;
            }
            spart[tid] = make_float2(s, q);
        }
        __syncthreads();   // SYNC_S1
        if (tid < 81) {
            float2 p0 = spart[tid*4], p1 = spart[tid*4+1], p2 = spart[tid*4+2], p3 = spart[tid*4+3];
            float s = p0.x+p1.x+p2.x+p3.x, q = p0.y+p1.y+p2.y+p3.y;
            float m = s * (1.f/192.f);
            float var = q * (1.f/192.f) - m*m;
            ssum[tid] = m; ssq[tid] = rsqrtf(var + 1e-5f);
        }
        __syncthreads();   // SYNC_S2

        // ===== Phase D: LayerNorm -> new h (bf16) =====
        for (int e = tid; e < 15552; e += 512) {
            int n = e / 192, j = e - n*192;
            float hc = hcf[HFI(n, j)];
            float hn2 = (hc - ssum[n]) * ssq[n] * gns[j] + bens[j];
            hb[HBI(n, j)] = f2bf(hn2);
        }
        __syncthreads();   // SYNC_D

        // ===== Phase E: logits = h @ W_out + b_out (waves 0-5) =====
        if (wave < 6) {
            int rt = wave;
            f32x4 acc = {0.f, 0.f, 0.f, 0.f};
#pragma unroll
            for (int ks = 0; ks < 6; ks++) {
                bf16x8 ha = ldsfrag(hb, rt, ks, lane);
                acc = __builtin_amdgcn_mfma_f32_16x16x32_bf16(ha, wfragN(Woutb, 0, 6, ks, lane), acc, 0,0,0);
            }
            if (l15 < 9) {
                float bo = b_out[l15];
#pragma unroll
                for (int i2 = 0; i2 < 4; i2++) {
                    int row = rt*16 + q4 + i2;
                    if (row < 81) {
                        float v = acc[i2] + bo;
                        out_all[((size_t)t*NNODES + (size_t)g*81 + row)*9 + l15] = v;
                        if (t == NSTEPS-1)
                            out_last[((size_t)g*81 + row)*9 + l15] = v;
                    }
                }
            }
        }
    }
}

// ---------------------------------------------------------------------------
extern "C" void kernel_launch(void* const* d_in, const int* in_sizes, int n_in,
                              void* d_out, int out_size, void* d_ws, size_t ws_size,
                              hipStream_t stream) {
    const float* x     = (const float*)d_in[0];
    const float* W_in  = (const float*)d_in[2];
    const float* b_in  = (const float*)d_in[3];
    const float* g_in  = (const float*)d_in[4];
    const float* be_in = (const float*)d_in[5];
    const float* pos   = (const float*)d_in[6];
    const float* W_m1  = (const float*)d_in[7];
    const float* b_m1  = (const float*)d_in[8];
    const float* W_m2  = (const float*)d_in[9];
    const float* b_m2  = (const float*)d_in[10];
    const float* W_ih  = (const float*)d_in[11];
    const float* W_hh  = (const float*)d_in[12];
    const float* b_ih  = (const float*)d_in[13];
    const float* b_hh  = (const float*)d_in[14];
    const float* g_n   = (const float*)d_in[15];
    const float* be_n  = (const float*)d_in[16];
    const float* W_out = (const float*)d_in[17];
    const float* b_out = (const float*)d_in[18];

    char* ws = (char*)d_ws;
    float*    Wfused = (float*)ws;                   // 442368
    ushort_t* Wm1b   = (ushort_t*)(ws + 442368);     // 147456
    ushort_t* Wr     = (ushort_t*)(ws + 589824);     // 147456
    ushort_t* Wz     = (ushort_t*)(ws + 737280);     // 147456
    ushort_t* Wni    = (ushort_t*)(ws + 884736);     // 73728
    ushort_t* Wnh    = (ushort_t*)(ws + 958464);     // 73728
    ushort_t* Woutb  = (ushort_t*)(ws + 1032192);    // 6144
    float*    bias_f = (float*)(ws + 1038336);       // 2304

    float* out_last = (float*)d_out;                 // (5184, 9)
    float* out_all  = (float*)d_out + NNODES*9;      // (16, 5184, 9)

    // Wfused = W_m2 @ W_ih^T   (192 x 576, fp32)
    k_gemm<true><<<dim3(3, 9), 256, 0, stream>>>(W_m2, W_ih, nullptr, 0.f, Wfused, 576);
    // weight -> bf16 fragment layouts + fused bias
    k_prep<<<(298560 + 255)/256, 256, 0, stream>>>(W_m1, Wfused, W_hh, W_out, W_ih, b_m2, b_ih,
                                                   Wm1b, Wr, Wz, Wni, Wnh, Woutb, bias_f);

    const int LDS_BYTES = 134568;
    hipFuncSetAttribute(reinterpret_cast<const void*>(k_main),
                        hipFuncAttributeMaxDynamicSharedMemorySize, LDS_BYTES);
    k_main<<<64, 512, LDS_BYTES, stream>>>(x, W_in, b_in, g_in, be_in, pos, b_m1, g_n, be_n,
                                           b_hh, b_out, Wm1b, Wr, Wz, Wni, Wnh, Woutb, bias_f,
                                           out_all, out_last);
}

// Round 7
// 1130.207 us; speedup vs baseline: 2.2762x; 2.1568x over previous
//
#include <hip/hip_runtime.h>
#include <hip/hip_bf16.h>
#include <math.h>

#define HID 192
#define NNODES 5184
#define NSTEPS 16

typedef float f32x4 __attribute__((ext_vector_type(4)));
typedef __bf16 bf16x8 __attribute__((ext_vector_type(8)));
typedef unsigned short ushort_t;
typedef ushort_t us8 __attribute__((ext_vector_type(8)));

__device__ __forceinline__ ushort_t f2bf(float f){
    __hip_bfloat16 h = __float2bfloat16(f);
    return __builtin_bit_cast(ushort_t, h);
}
__device__ __forceinline__ float bf2f(ushort_t u){
    return __uint_as_float(((unsigned)u) << 16);
}

// swizzled index helpers (bank-conflict-free fragment reads)
#define HFI(r,c) ((r)*192 + ((c) ^ (((r)&7)<<2)))   // f32 buffer [81][192]
#define ABI(r,c) ((r)*384 + ((c) ^ (((r)&7)<<3)))   // bf16 buffer [81][384]
#define HBI(r,c) ((r)*192 + ((c) ^ (((r)&7)<<3)))   // bf16 buffer [81][192]

// load MFMA A-fragment (16x32 bf16) from a [81][192] bf16 LDS buffer (HBI swizzle)
__device__ __forceinline__ bf16x8 ldsfrag(const ushort_t* buf, int rt, int ks, int lane){
    int r = rt*16 + (lane & 15);
    int k0 = ks*32 + ((lane >> 4) << 3);
    if (r < 81) return *(const bf16x8*)&buf[HBI(r, k0)];
    us8 z = {0,0,0,0,0,0,0,0};
    return __builtin_bit_cast(bf16x8, z);
}
// pre-permuted weight fragment: array of [ct][nks][64][8]
__device__ __forceinline__ bf16x8 wfragN(const ushort_t* W, int ct, int nks, int ks, int lane){
    return *(const bf16x8*)&W[(size_t)(((ct*nks) + ks)*64 + lane)*8];
}

// ---------------------------------------------------------------------------
// fp32 tiled GEMM -- used once for Wfused = W_m2 @ W_ih^T
// ---------------------------------------------------------------------------
template <bool TRANSB>
__global__ __launch_bounds__(256)
void k_gemm(const float* __restrict__ A, const float* __restrict__ B,
            const float* __restrict__ bias, float biasScale,
            float* __restrict__ C, int N) {
    const int K = HID;
    __shared__ float As[64][17];
    __shared__ float Bs[16][65];
    int tid = threadIdx.x;
    int tx = tid & 15, ty = tid >> 4;
    int rowBase = blockIdx.x * 64;
    int colBase = blockIdx.y * 64;
    float acc[4][4] = {};
    for (int k0 = 0; k0 < K; k0 += 16) {
        {
            int r = tid >> 2, kk = (tid & 3) << 2;
            const float4 av = *(const float4*)&A[(size_t)(rowBase + r) * K + k0 + kk];
            As[r][kk + 0] = av.x; As[r][kk + 1] = av.y;
            As[r][kk + 2] = av.z; As[r][kk + 3] = av.w;
        }
        if (!TRANSB) {
            int kk = tid >> 4, j4 = (tid & 15) << 2;
            const float4 bv = *(const float4*)&B[(size_t)(k0 + kk) * N + colBase + j4];
            Bs[kk][j4 + 0] = bv.x; Bs[kk][j4 + 1] = bv.y;
            Bs[kk][j4 + 2] = bv.z; Bs[kk][j4 + 3] = bv.w;
        } else {
            int jj = tid >> 2, kk = (tid & 3) << 2;
            const float4 bv = *(const float4*)&B[(size_t)(colBase + jj) * K + k0 + kk];
            Bs[kk + 0][jj] = bv.x; Bs[kk + 1][jj] = bv.y;
            Bs[kk + 2][jj] = bv.z; Bs[kk + 3][jj] = bv.w;
        }
        __syncthreads();
#pragma unroll
        for (int kk = 0; kk < 16; kk++) {
            float a0 = As[ty*4+0][kk], a1 = As[ty*4+1][kk];
            float a2 = As[ty*4+2][kk], a3 = As[ty*4+3][kk];
            float b0 = Bs[kk][tx*4+0], b1 = Bs[kk][tx*4+1];
            float b2 = Bs[kk][tx*4+2], b3 = Bs[kk][tx*4+3];
            acc[0][0]+=a0*b0; acc[0][1]+=a0*b1; acc[0][2]+=a0*b2; acc[0][3]+=a0*b3;
            acc[1][0]+=a1*b0; acc[1][1]+=a1*b1; acc[1][2]+=a1*b2; acc[1][3]+=a1*b3;
            acc[2][0]+=a2*b0; acc[2][1]+=a2*b1; acc[2][2]+=a2*b2; acc[2][3]+=a2*b3;
            acc[3][0]+=a3*b0; acc[3][1]+=a3*b1; acc[3][2]+=a3*b2; acc[3][3]+=a3*b3;
        }
        __syncthreads();
    }
    float4 bb = make_float4(0.f,0.f,0.f,0.f);
    if (bias) {
        bb = *(const float4*)&bias[colBase + tx*4];
        bb.x*=biasScale; bb.y*=biasScale; bb.z*=biasScale; bb.w*=biasScale;
    }
#pragma unroll
    for (int i = 0; i < 4; i++) {
        int r = rowBase + ty*4 + i;
        float4 o;
        o.x=acc[i][0]+bb.x; o.y=acc[i][1]+bb.y; o.z=acc[i][2]+bb.z; o.w=acc[i][3]+bb.w;
        *(float4*)&C[(size_t)r * N + colBase + tx*4] = o;
    }
}

// ---------------------------------------------------------------------------
// prep: permute weights into MFMA B-fragment layouts (validated r2-r6).
// ---------------------------------------------------------------------------
__global__ void k_prep(const float* __restrict__ W_m1, const float* __restrict__ Wfused,
                       const float* __restrict__ W_hh, const float* __restrict__ W_out,
                       const float* __restrict__ W_ih, const float* __restrict__ b_m2,
                       const float* __restrict__ b_ih,
                       ushort_t* __restrict__ Wm1b, ushort_t* __restrict__ Wr,
                       ushort_t* __restrict__ Wz, ushort_t* __restrict__ Wni,
                       ushort_t* __restrict__ Wnh, ushort_t* __restrict__ Woutb,
                       float* __restrict__ bias_f) {
    int t = blockIdx.x * 256 + threadIdx.x;
    const int n0 = 73728;            // Wm1b
    const int n1 = n0 + 73728;       // Wr
    const int n2 = n1 + 73728;       // Wz
    const int n3 = n2 + 36864;       // Wni
    const int n4 = n3 + 36864;       // Wnh
    const int n5 = n4 + 3072;        // Woutb
    const int n6 = n5 + 576;         // bias_f
    if (t < n0) {
        int idx = t;
        int e = idx & 7, lane = (idx >> 3) & 63, cs = idx >> 9;
        int ct = cs / 6, ks = cs - ct*6;
        int k = ks*32 + ((lane>>4)<<3) + e, col = ct*16 + (lane & 15);
        float v = (col < 192) ? W_m1[k*192 + col] : W_m1[(192 + k)*192 + (col - 192)];
        Wm1b[idx] = f2bf(v);
    } else if (t < n1) {
        int idx = t - n0;
        int e = idx & 7, lane = (idx >> 3) & 63, cs = idx >> 9;
        int ct = cs / 12, ks = cs - ct*12;
        int k = ks*32 + ((lane>>4)<<3) + e, col = ct*16 + (lane & 15);
        float v = (k < 192) ? Wfused[k*576 + col] : W_hh[col*192 + (k - 192)];
        Wr[idx] = f2bf(v);
    } else if (t < n2) {
        int idx = t - n1;
        int e = idx & 7, lane = (idx >> 3) & 63, cs = idx >> 9;
        int ct = cs / 12, ks = cs - ct*12;
        int k = ks*32 + ((lane>>4)<<3) + e, col = ct*16 + (lane & 15);
        float v = (k < 192) ? Wfused[k*576 + 192 + col] : W_hh[(192 + col)*192 + (k - 192)];
        Wz[idx] = f2bf(v);
    } else if (t < n3) {
        int idx = t - n2;
        int e = idx & 7, lane = (idx >> 3) & 63, cs = idx >> 9;
        int ct = cs / 6, ks = cs - ct*6;
        int k = ks*32 + ((lane>>4)<<3) + e, col = ct*16 + (lane & 15);
        Wni[idx] = f2bf(Wfused[k*576 + 384 + col]);
    } else if (t < n4) {
        int idx = t - n3;
        int e = idx & 7, lane = (idx >> 3) & 63, cs = idx >> 9;
        int ct = cs / 6, ks = cs - ct*6;
        int k = ks*32 + ((lane>>4)<<3) + e, col = ct*16 + (lane & 15);
        Wnh[idx] = f2bf(W_hh[(384 + col)*192 + k]);
    } else if (t < n5) {
        int idx = t - n4;
        int e = idx & 7, lane = (idx >> 3) & 63, ks = idx >> 9;
        int k = ks*32 + ((lane>>4)<<3) + e, col = lane & 15;
        Woutb[idx] = (col < 9) ? f2bf(W_out[k*9 + col]) : (ushort_t)0;
    } else if (t < n6) {
        int n = t - n5;
        float s = 0.f;
        for (int m = 0; m < 192; m++) s += b_m2[m] * W_ih[n*192 + m];
        bias_f[n] = 20.f * s + b_ih[n];
    }
}

// ---------------------------------------------------------------------------
// Monolithic RRN kernel -- 256 threads (4 waves) per block, one block/graph.
// 4-wave blocks need only 1 wave-slot/SIMD => per-wave register budget 512
// (vs 256 for 8-wave blocks) => phase working sets fit with headroom =>
// zero scratch => L2 stays clean => weight stream becomes L2-resident.
// LDS map (134568 B) identical to r6.
// ---------------------------------------------------------------------------
__global__ __launch_bounds__(256)
void k_main(const float* __restrict__ x, const float* __restrict__ W_in,
            const float* __restrict__ b_in, const float* __restrict__ g_in,
            const float* __restrict__ be_in, const float* __restrict__ pos,
            const float* __restrict__ b_m1, const float* __restrict__ g_n,
            const float* __restrict__ be_n, const float* __restrict__ b_hh,
            const float* __restrict__ b_out,
            const ushort_t* __restrict__ Wm1b, const ushort_t* __restrict__ Wr,
            const ushort_t* __restrict__ Wz, const ushort_t* __restrict__ Wni,
            const ushort_t* __restrict__ Wnh, const ushort_t* __restrict__ Woutb,
            const float* __restrict__ bias_f,
            float* __restrict__ out_all, float* __restrict__ out_last)
{
    extern __shared__ char smem[];
    ushort_t* Rb    = (ushort_t*)(smem);
    ushort_t* AB    = (ushort_t*)(smem + 31104);
    float*    hcf   = (float*)(smem + 31104);        // overlays AB
    ushort_t* hb    = (ushort_t*)(smem + 93312);
    float2*   spart = (float2*)(smem + 124416);
    float* ssum   = (float*)(smem + 127008);
    float* ssq    = (float*)(smem + 127332);
    float* bm1s   = (float*)(smem + 127656);
    float* gns    = (float*)(smem + 128424);
    float* bens   = (float*)(smem + 129192);
    float* biasfs = (float*)(smem + 129960);
    float* bhhs   = (float*)(smem + 132264);

    const int tid = threadIdx.x;
    const int lane = tid & 63, wave = tid >> 6;      // wave in [0,4)
    const int l15 = lane & 15, q4 = (lane >> 4) << 2;
    const int g = blockIdx.x;

    if (tid < 192) { bm1s[tid] = b_m1[tid]; gns[tid] = g_n[tid]; bens[tid] = be_n[tid]; }
    for (int e = tid; e < 576; e += 256) { biasfs[e] = bias_f[e]; bhhs[e] = b_hh[e]; }

    // ---------------- h0 = LN(x@W_in + b_in)*g+be + pos ----------------
    {
        float* xs = (float*)Rb;           // x staging (3240 B)
        float* vf = hcf;                  // f32 scratch (linear use)
        for (int e = tid; e < 810; e += 256) xs[e] = x[(size_t)g*810 + e];
        __syncthreads();
        for (int e = tid; e < 15552; e += 256) {
            int n = e / 192, j = e - n*192;
            float v = b_in[j];
#pragma unroll
            for (int k = 0; k < 10; k++) v += xs[n*10 + k] * W_in[k*192 + j];
            vf[n*192 + j] = v;
        }
        __syncthreads();
        if (tid < 162) {
            int row = tid >> 1, part = tid & 1;
            float s = 0.f, q = 0.f;
#pragma unroll
            for (int i = 0; i < 24; i++) {
                float4 v = *(float4*)&vf[row*192 + part*96 + i*4];
                s += v.x + v.y + v.z + v.w;
                q += v.x*v.x + v.y*v.y + v.z*v.z + v.w*v.w;
            }
            spart[tid] = make_float2(s, q);
        }
        __syncthreads();
        if (tid < 81) {
            float2 p0 = spart[tid*2], p1 = spart[tid*2+1];
            float s = p0.x+p1.x, q = p0.y+p1.y;
            float m = s * (1.f/192.f);
            float var = q * (1.f/192.f) - m*m;
            ssum[tid] = m; ssq[tid] = rsqrtf(var + 1e-5f);
        }
        __syncthreads();
        for (int e = tid; e < 15552; e += 256) {
            int n = e / 192, j = e - n*192;
            float v = vf[n*192 + j];
            v = (v - ssum[n]) * ssq[n] * g_in[j] + be_in[j] + pos[n*192 + j];
            hb[HBI(n, j)] = f2bf(v);
        }
        __syncthreads();
    }

    for (int t = 0; t < NSTEPS; t++) {
        // ===== Phase A: [A|B] = h @ Wm1comb : 24 col-tiles, 6 per wave =====
        for (int c = 0; c < 6; c++) {
            int ct = wave*6 + c;
            bf16x8 wbc[6];
#pragma unroll
            for (int ks = 0; ks < 6; ks++)
                wbc[ks] = wfragN(Wm1b, ct, 6, ks, lane);
            int col = ct*16 + l15;
            float addb = (col >= 192) ? bm1s[col - 192] : 0.f;
#pragma unroll
            for (int rt = 0; rt < 6; rt++) {
                f32x4 acc = {0.f, 0.f, 0.f, 0.f};
#pragma unroll
                for (int ks = 0; ks < 6; ks++)
                    acc = __builtin_amdgcn_mfma_f32_16x16x32_bf16(ldsfrag(hb, rt, ks, lane), wbc[ks], acc, 0, 0, 0);
#pragma unroll
                for (int i2 = 0; i2 < 4; i2++) {
                    int row = rt*16 + q4 + i2;
                    if (row < 81) AB[ABI(row, col)] = f2bf(acc[i2] + addb);
                }
            }
        }
        __syncthreads();   // SYNC_A

        // ===== Phase B: Rb[d] = sum_{s in nbr(d)} relu(A[s] + B[d]) =====
        for (int it = 0; it < 8; it++) {
            int e = tid + 256*it;
            if (e < 1944) {
                int d = e / 24, j8 = e - d*24;
                int j0 = j8 * 8;
                float bsum[8], r8[8] = {0,0,0,0,0,0,0,0};
                us8 bu = *(const us8*)&AB[ABI(d, 192 + j0)];
#pragma unroll
                for (int i = 0; i < 8; i++) bsum[i] = bf2f(bu[i]);
                int rr = d / 9, cc = d - rr*9;
                int rb0 = (rr/3)*3, cb0 = (cc/3)*3;
#pragma unroll
                for (int c2 = 0; c2 < 9; c2++) {
                    if (c2 == cc) continue;
                    us8 au = *(const us8*)&AB[ABI(rr*9 + c2, j0)];
#pragma unroll
                    for (int i = 0; i < 8; i++) r8[i] += fmaxf(bf2f(au[i]) + bsum[i], 0.f);
                }
#pragma unroll
                for (int r2 = 0; r2 < 9; r2++) {
                    if (r2 == rr) continue;
                    us8 au = *(const us8*)&AB[ABI(r2*9 + cc, j0)];
#pragma unroll
                    for (int i = 0; i < 8; i++) r8[i] += fmaxf(bf2f(au[i]) + bsum[i], 0.f);
                }
#pragma unroll
                for (int r2 = 0; r2 < 3; r2++) {
                    int rrr = rb0 + r2;
                    if (rrr == rr) continue;
#pragma unroll
                    for (int c2 = 0; c2 < 3; c2++) {
                        int ccc = cb0 + c2;
                        if (ccc == cc) continue;
                        us8 au = *(const us8*)&AB[ABI(rrr*9 + ccc, j0)];
#pragma unroll
                        for (int i = 0; i < 8; i++) r8[i] += fmaxf(bf2f(au[i]) + bsum[i], 0.f);
                    }
                }
                us8 w;
#pragma unroll
                for (int i = 0; i < 8; i++) w[i] = f2bf(r8[i]);
                *(us8*)&Rb[HBI(d, j0)] = w;
            }
        }
        __syncthreads();   // SYNC_B  (AB dead; hcf overlays it)

        // ===== Phase C: 24 units (12 ct x 2 row-halves), 6 per wave =====
        for (int uu = 0; uu < 6; uu++) {
            int u = wave + uu*4;                 // 0..23
            int ct = (u < 12) ? u : (u - 12);
            int rh = (u < 12) ? 0 : 1;
            int col = ct*16 + l15;
            // pass 1: r,z gates over K=384 ([Rb | hb])
            f32x4 ar[3] = {}, az[3] = {};
#pragma unroll
            for (int ks = 0; ks < 12; ks++) {
                bf16x8 wfr = wfragN(Wr, ct, 12, ks, lane);
                bf16x8 wfz = wfragN(Wz, ct, 12, ks, lane);
#pragma unroll
                for (int r3 = 0; r3 < 3; r3++) {
                    int rt = rh*3 + r3;
                    bf16x8 af = (ks < 6) ? ldsfrag(Rb, rt, ks, lane)
                                         : ldsfrag(hb, rt, ks - 6, lane);
                    ar[r3] = __builtin_amdgcn_mfma_f32_16x16x32_bf16(af, wfr, ar[r3], 0,0,0);
                    az[r3] = __builtin_amdgcn_mfma_f32_16x16x32_bf16(af, wfz, az[r3], 0,0,0);
                }
            }
            // pass 2: n gate (inn over Rb, hn over hb)
            f32x4 ani[3] = {}, anh[3] = {};
#pragma unroll
            for (int ks = 0; ks < 6; ks++) {
                bf16x8 wni = wfragN(Wni, ct, 6, ks, lane);
                bf16x8 wnh = wfragN(Wnh, ct, 6, ks, lane);
#pragma unroll
                for (int r3 = 0; r3 < 3; r3++) {
                    int rt = rh*3 + r3;
                    ani[r3] = __builtin_amdgcn_mfma_f32_16x16x32_bf16(ldsfrag(Rb, rt, ks, lane), wni, ani[r3], 0,0,0);
                    anh[r3] = __builtin_amdgcn_mfma_f32_16x16x32_bf16(ldsfrag(hb, rt, ks, lane), wnh, anh[r3], 0,0,0);
                }
            }
            float br  = biasfs[col]       + bhhs[col];
            float bz  = biasfs[col + 192] + bhhs[col + 192];
            float bni = biasfs[col + 384];
            float bnh = bhhs[col + 384];
#pragma unroll
            for (int r3 = 0; r3 < 3; r3++) {
#pragma unroll
                for (int i2 = 0; i2 < 4; i2++) {
                    int row = (rh*3 + r3)*16 + q4 + i2;
                    if (row < 81) {
                        float hv = bf2f(hb[HBI(row, col)]);
                        float rg = 1.f/(1.f + __expf(-(ar[r3][i2] + br)));
                        float zg = 1.f/(1.f + __expf(-(az[r3][i2] + bz)));
                        float e2 = __expf(2.f*(ani[r3][i2] + bni + rg*(anh[r3][i2] + bnh)));
                        float ng = 1.f - 2.f/(e2 + 1.f);
                        hcf[HFI(row, col)] = (1.f - zg)*ng + zg*hv;
                    }
                }
            }
        }
        __syncthreads();   // SYNC_C

        // ===== LN stats (162-thread partial pass over hcf) =====
        if (tid < 162) {
            int row = tid >> 1, part = tid & 1;
            float s = 0.f, q = 0.f;
#pragma unroll
            for (int i = 0; i < 24; i++) {
                float4 v = *(float4*)&hcf[HFI(row, part*96 + i*4)];
                s += v.x + v.y + v.z + v.w;
                q += v.x*v.x + v.y*v.y + v.z*v.z + v.w*v.w;
            }
            spart[tid] = make_float2(s, q);
        }
        __syncthreads();   // SYNC_S1
        if (tid < 81) {
            float2 p0 = spart[tid*2], p1 = spart[tid*2+1];
            float s = p0.x+p1.x, q = p0.y+p1.y;
            float m = s * (1.f/192.f);
            float var = q * (1.f/192.f) - m*m;
            ssum[tid] = m; ssq[tid] = rsqrtf(var + 1e-5f);
        }
        __syncthreads();   // SYNC_S2

        // ===== Phase D: LayerNorm -> new h (bf16) =====
        for (int e = tid; e < 15552; e += 256) {
            int n = e / 192, j = e - n*192;
            float hc = hcf[HFI(n, j)];
            float hn2 = (hc - ssum[n]) * ssq[n] * gns[j] + bens[j];
            hb[HBI(n, j)] = f2bf(hn2);
        }
        __syncthreads();   // SYNC_D

        // ===== Phase E: logits = h @ W_out + b_out =====
#pragma unroll
        for (int rep = 0; rep < 2; rep++) {
            int rt = wave + rep*4;
            if (rt < 6) {
                f32x4 acc = {0.f, 0.f, 0.f, 0.f};
#pragma unroll
                for (int ks = 0; ks < 6; ks++) {
                    bf16x8 ha = ldsfrag(hb, rt, ks, lane);
                    acc = __builtin_amdgcn_mfma_f32_16x16x32_bf16(ha, wfragN(Woutb, 0, 6, ks, lane), acc, 0,0,0);
                }
                if (l15 < 9) {
                    float bo = b_out[l15];
#pragma unroll
                    for (int i2 = 0; i2 < 4; i2++) {
                        int row = rt*16 + q4 + i2;
                        if (row < 81) {
                            float v = acc[i2] + bo;
                            out_all[((size_t)t*NNODES + (size_t)g*81 + row)*9 + l15] = v;
                            if (t == NSTEPS-1)
                                out_last[((size_t)g*81 + row)*9 + l15] = v;
                        }
                    }
                }
            }
        }
    }
}

// ---------------------------------------------------------------------------
extern "C" void kernel_launch(void* const* d_in, const int* in_sizes, int n_in,
                              void* d_out, int out_size, void* d_ws, size_t ws_size,
                              hipStream_t stream) {
    const float* x     = (const float*)d_in[0];
    const float* W_in  = (const float*)d_in[2];
    const float* b_in  = (const float*)d_in[3];
    const float* g_in  = (const float*)d_in[4];
    const float* be_in = (const float*)d_in[5];
    const float* pos   = (const float*)d_in[6];
    const float* W_m1  = (const float*)d_in[7];
    const float* b_m1  = (const float*)d_in[8];
    const float* W_m2  = (const float*)d_in[9];
    const float* b_m2  = (const float*)d_in[10];
    const float* W_ih  = (const float*)d_in[11];
    const float* W_hh  = (const float*)d_in[12];
    const float* b_ih  = (const float*)d_in[13];
    const float* b_hh  = (const float*)d_in[14];
    const float* g_n   = (const float*)d_in[15];
    const float* be_n  = (const float*)d_in[16];
    const float* W_out = (const float*)d_in[17];
    const float* b_out = (const float*)d_in[18];

    char* ws = (char*)d_ws;
    float*    Wfused = (float*)ws;                   // 442368
    ushort_t* Wm1b   = (ushort_t*)(ws + 442368);     // 147456
    ushort_t* Wr     = (ushort_t*)(ws + 589824);     // 147456
    ushort_t* Wz     = (ushort_t*)(ws + 737280);     // 147456
    ushort_t* Wni    = (ushort_t*)(ws + 884736);     // 73728
    ushort_t* Wnh    = (ushort_t*)(ws + 958464);     // 73728
    ushort_t* Woutb  = (ushort_t*)(ws + 1032192);    // 6144
    float*    bias_f = (float*)(ws + 1038336);       // 2304

    float* out_last = (float*)d_out;                 // (5184, 9)
    float* out_all  = (float*)d_out + NNODES*9;      // (16, 5184, 9)

    // Wfused = W_m2 @ W_ih^T   (192 x 576, fp32)
    k_gemm<true><<<dim3(3, 9), 256, 0, stream>>>(W_m2, W_ih, nullptr, 0.f, Wfused, 576);
    // weight -> bf16 fragment layouts + fused bias
    k_prep<<<(298560 + 255)/256, 256, 0, stream>>>(W_m1, Wfused, W_hh, W_out, W_ih, b_m2, b_ih,
                                                   Wm1b, Wr, Wz, Wni, Wnh, Woutb, bias_f);

    const int LDS_BYTES = 134568;
    hipFuncSetAttribute(reinterpret_cast<const void*>(k_main),
                        hipFuncAttributeMaxDynamicSharedMemorySize, LDS_BYTES);
    k_main<<<64, 256, LDS_BYTES, stream>>>(x, W_in, b_in, g_in, be_in, pos, b_m1, g_n, be_n,
                                           b_hh, b_out, Wm1b, Wr, Wz, Wni, Wnh, Woutb, bias_f,
                                           out_all, out_last);
}

// Round 8
// 853.563 us; speedup vs baseline: 3.0140x; 1.3241x over previous
//
#include <hip/hip_runtime.h>
#include <hip/hip_bf16.h>
#include <math.h>

#define HID 192
#define NNODES 5184
#define NSTEPS 16

typedef float f32x4 __attribute__((ext_vector_type(4)));
typedef __bf16 bf16x8 __attribute__((ext_vector_type(8)));
typedef unsigned short ushort_t;
typedef ushort_t us8 __attribute__((ext_vector_type(8)));

__device__ __forceinline__ ushort_t f2bf(float f){
    __hip_bfloat16 h = __float2bfloat16(f);
    return __builtin_bit_cast(ushort_t, h);
}
__device__ __forceinline__ float bf2f(ushort_t u){
    return __uint_as_float(((unsigned)u) << 16);
}

// swizzled index helpers (bank-conflict-free fragment reads)
#define HFI(r,c) ((r)*192 + ((c) ^ (((r)&7)<<2)))   // f32 buffer [81][192]
#define ABI(r,c) ((r)*384 + ((c) ^ (((r)&7)<<3)))   // bf16 buffer [81][384]
#define HBI(r,c) ((r)*192 + ((c) ^ (((r)&7)<<3)))   // bf16 buffer [81][192]

// load MFMA A-fragment (16x32 bf16) from a [81][192] bf16 LDS buffer (HBI swizzle)
__device__ __forceinline__ bf16x8 ldsfrag(const ushort_t* buf, int rt, int ks, int lane){
    int r = rt*16 + (lane & 15);
    int k0 = ks*32 + ((lane >> 4) << 3);
    if (r < 81) return *(const bf16x8*)&buf[HBI(r, k0)];
    us8 z = {0,0,0,0,0,0,0,0};
    return __builtin_bit_cast(bf16x8, z);
}
// pre-permuted weight fragment: array of [ct][nks][64][8]
__device__ __forceinline__ bf16x8 wfragN(const ushort_t* W, int ct, int nks, int ks, int lane){
    return *(const bf16x8*)&W[(size_t)(((ct*nks) + ks)*64 + lane)*8];
}

// ---------------------------------------------------------------------------
// fp32 tiled GEMM -- used once for Wfused = W_m2 @ W_ih^T
// ---------------------------------------------------------------------------
template <bool TRANSB>
__global__ __launch_bounds__(256)
void k_gemm(const float* __restrict__ A, const float* __restrict__ B,
            const float* __restrict__ bias, float biasScale,
            float* __restrict__ C, int N) {
    const int K = HID;
    __shared__ float As[64][17];
    __shared__ float Bs[16][65];
    int tid = threadIdx.x;
    int tx = tid & 15, ty = tid >> 4;
    int rowBase = blockIdx.x * 64;
    int colBase = blockIdx.y * 64;
    float acc[4][4] = {};
    for (int k0 = 0; k0 < K; k0 += 16) {
        {
            int r = tid >> 2, kk = (tid & 3) << 2;
            const float4 av = *(const float4*)&A[(size_t)(rowBase + r) * K + k0 + kk];
            As[r][kk + 0] = av.x; As[r][kk + 1] = av.y;
            As[r][kk + 2] = av.z; As[r][kk + 3] = av.w;
        }
        if (!TRANSB) {
            int kk = tid >> 4, j4 = (tid & 15) << 2;
            const float4 bv = *(const float4*)&B[(size_t)(k0 + kk) * N + colBase + j4];
            Bs[kk][j4 + 0] = bv.x; Bs[kk][j4 + 1] = bv.y;
            Bs[kk][j4 + 2] = bv.z; Bs[kk][j4 + 3] = bv.w;
        } else {
            int jj = tid >> 2, kk = (tid & 3) << 2;
            const float4 bv = *(const float4*)&B[(size_t)(colBase + jj) * K + k0 + kk];
            Bs[kk + 0][jj] = bv.x; Bs[kk + 1][jj] = bv.y;
            Bs[kk + 2][jj] = bv.z; Bs[kk + 3][jj] = bv.w;
        }
        __syncthreads();
#pragma unroll
        for (int kk = 0; kk < 16; kk++) {
            float a0 = As[ty*4+0][kk], a1 = As[ty*4+1][kk];
            float a2 = As[ty*4+2][kk], a3 = As[ty*4+3][kk];
            float b0 = Bs[kk][tx*4+0], b1 = Bs[kk][tx*4+1];
            float b2 = Bs[kk][tx*4+2], b3 = Bs[kk][tx*4+3];
            acc[0][0]+=a0*b0; acc[0][1]+=a0*b1; acc[0][2]+=a0*b2; acc[0][3]+=a0*b3;
            acc[1][0]+=a1*b0; acc[1][1]+=a1*b1; acc[1][2]+=a1*b2; acc[1][3]+=a1*b3;
            acc[2][0]+=a2*b0; acc[2][1]+=a2*b1; acc[2][2]+=a2*b2; acc[2][3]+=a2*b3;
            acc[3][0]+=a3*b0; acc[3][1]+=a3*b1; acc[3][2]+=a3*b2; acc[3][3]+=a3*b3;
        }
        __syncthreads();
    }
    float4 bb = make_float4(0.f,0.f,0.f,0.f);
    if (bias) {
        bb = *(const float4*)&bias[colBase + tx*4];
        bb.x*=biasScale; bb.y*=biasScale; bb.z*=biasScale; bb.w*=biasScale;
    }
#pragma unroll
    for (int i = 0; i < 4; i++) {
        int r = rowBase + ty*4 + i;
        float4 o;
        o.x=acc[i][0]+bb.x; o.y=acc[i][1]+bb.y; o.z=acc[i][2]+bb.z; o.w=acc[i][3]+bb.w;
        *(float4*)&C[(size_t)r * N + colBase + tx*4] = o;
    }
}

// ---------------------------------------------------------------------------
// prep: permute weights into MFMA B-fragment layouts (validated r2-r7).
// ---------------------------------------------------------------------------
__global__ void k_prep(const float* __restrict__ W_m1, const float* __restrict__ Wfused,
                       const float* __restrict__ W_hh, const float* __restrict__ W_out,
                       const float* __restrict__ W_ih, const float* __restrict__ b_m2,
                       const float* __restrict__ b_ih,
                       ushort_t* __restrict__ Wm1b, ushort_t* __restrict__ Wr,
                       ushort_t* __restrict__ Wz, ushort_t* __restrict__ Wni,
                       ushort_t* __restrict__ Wnh, ushort_t* __restrict__ Woutb,
                       float* __restrict__ bias_f) {
    int t = blockIdx.x * 256 + threadIdx.x;
    const int n0 = 73728;            // Wm1b
    const int n1 = n0 + 73728;       // Wr
    const int n2 = n1 + 73728;       // Wz
    const int n3 = n2 + 36864;       // Wni
    const int n4 = n3 + 36864;       // Wnh
    const int n5 = n4 + 3072;        // Woutb
    const int n6 = n5 + 576;         // bias_f
    if (t < n0) {
        int idx = t;
        int e = idx & 7, lane = (idx >> 3) & 63, cs = idx >> 9;
        int ct = cs / 6, ks = cs - ct*6;
        int k = ks*32 + ((lane>>4)<<3) + e, col = ct*16 + (lane & 15);
        float v = (col < 192) ? W_m1[k*192 + col] : W_m1[(192 + k)*192 + (col - 192)];
        Wm1b[idx] = f2bf(v);
    } else if (t < n1) {
        int idx = t - n0;
        int e = idx & 7, lane = (idx >> 3) & 63, cs = idx >> 9;
        int ct = cs / 12, ks = cs - ct*12;
        int k = ks*32 + ((lane>>4)<<3) + e, col = ct*16 + (lane & 15);
        float v = (k < 192) ? Wfused[k*576 + col] : W_hh[col*192 + (k - 192)];
        Wr[idx] = f2bf(v);
    } else if (t < n2) {
        int idx = t - n1;
        int e = idx & 7, lane = (idx >> 3) & 63, cs = idx >> 9;
        int ct = cs / 12, ks = cs - ct*12;
        int k = ks*32 + ((lane>>4)<<3) + e, col = ct*16 + (lane & 15);
        float v = (k < 192) ? Wfused[k*576 + 192 + col] : W_hh[(192 + col)*192 + (k - 192)];
        Wz[idx] = f2bf(v);
    } else if (t < n3) {
        int idx = t - n2;
        int e = idx & 7, lane = (idx >> 3) & 63, cs = idx >> 9;
        int ct = cs / 6, ks = cs - ct*6;
        int k = ks*32 + ((lane>>4)<<3) + e, col = ct*16 + (lane & 15);
        Wni[idx] = f2bf(Wfused[k*576 + 384 + col]);
    } else if (t < n4) {
        int idx = t - n3;
        int e = idx & 7, lane = (idx >> 3) & 63, cs = idx >> 9;
        int ct = cs / 6, ks = cs - ct*6;
        int k = ks*32 + ((lane>>4)<<3) + e, col = ct*16 + (lane & 15);
        Wnh[idx] = f2bf(W_hh[(384 + col)*192 + k]);
    } else if (t < n5) {
        int idx = t - n4;
        int e = idx & 7, lane = (idx >> 3) & 63, ks = idx >> 9;
        int k = ks*32 + ((lane>>4)<<3) + e, col = lane & 15;
        Woutb[idx] = (col < 9) ? f2bf(W_out[k*9 + col]) : (ushort_t)0;
    } else if (t < n6) {
        int n = t - n5;
        float s = 0.f;
        for (int m = 0; m < 192; m++) s += b_m2[m] * W_ih[n*192 + m];
        bias_f[n] = 20.f * s + b_ih[n];
    }
}

// ---------------------------------------------------------------------------
// Monolithic RRN kernel -- 512 threads (8 waves, 2/SIMD for TLP).
// Register discipline for the 2-wave/SIMD budget (256 unified):
//   * ks-loops unroll-capped at 3 -> <=24 arch regs of weight frags in flight
//   * Phase C: each wave owns ct=wave for BOTH row-halves (weights shared,
//     acc[6] arrays live in AGPRs) + one odd unit (ct 8..11)
//   * no register array lives across a barrier
// LDS map (134568 B) identical to r6/r7.
// ---------------------------------------------------------------------------
__global__ __launch_bounds__(512)
void k_main(const float* __restrict__ x, const float* __restrict__ W_in,
            const float* __restrict__ b_in, const float* __restrict__ g_in,
            const float* __restrict__ be_in, const float* __restrict__ pos,
            const float* __restrict__ b_m1, const float* __restrict__ g_n,
            const float* __restrict__ be_n, const float* __restrict__ b_hh,
            const float* __restrict__ b_out,
            const ushort_t* __restrict__ Wm1b, const ushort_t* __restrict__ Wr,
            const ushort_t* __restrict__ Wz, const ushort_t* __restrict__ Wni,
            const ushort_t* __restrict__ Wnh, const ushort_t* __restrict__ Woutb,
            const float* __restrict__ bias_f,
            float* __restrict__ out_all, float* __restrict__ out_last)
{
    extern __shared__ char smem[];
    ushort_t* Rb    = (ushort_t*)(smem);
    ushort_t* AB    = (ushort_t*)(smem + 31104);
    float*    hcf   = (float*)(smem + 31104);        // overlays AB
    ushort_t* hb    = (ushort_t*)(smem + 93312);
    float2*   spart = (float2*)(smem + 124416);
    float* ssum   = (float*)(smem + 127008);
    float* ssq    = (float*)(smem + 127332);
    float* bm1s   = (float*)(smem + 127656);
    float* gns    = (float*)(smem + 128424);
    float* bens   = (float*)(smem + 129192);
    float* biasfs = (float*)(smem + 129960);
    float* bhhs   = (float*)(smem + 132264);

    const int tid = threadIdx.x;
    const int lane = tid & 63, wave = tid >> 6;      // wave in [0,8)
    const int l15 = lane & 15, q4 = (lane >> 4) << 2;
    const int g = blockIdx.x;

    if (tid < 192) { bm1s[tid] = b_m1[tid]; gns[tid] = g_n[tid]; bens[tid] = be_n[tid]; }
    for (int e = tid; e < 576; e += 512) { biasfs[e] = bias_f[e]; bhhs[e] = b_hh[e]; }

    // ---------------- h0 = LN(x@W_in + b_in)*g+be + pos ----------------
    {
        float* xs = (float*)Rb;           // x staging (3240 B)
        float* vf = hcf;                  // f32 scratch (linear use)
        for (int e = tid; e < 810; e += 512) xs[e] = x[(size_t)g*810 + e];
        __syncthreads();
        for (int e = tid; e < 15552; e += 512) {
            int n = e / 192, j = e - n*192;
            float v = b_in[j];
#pragma unroll
            for (int k = 0; k < 10; k++) v += xs[n*10 + k] * W_in[k*192 + j];
            vf[n*192 + j] = v;
        }
        __syncthreads();
        if (tid < 324) {
            int row = tid >> 2, part = tid & 3;
            float s = 0.f, q = 0.f;
#pragma unroll
            for (int i = 0; i < 12; i++) {
                float4 v = *(float4*)&vf[row*192 + part*48 + i*4];
                s += v.x + v.y + v.z + v.w;
                q += v.x*v.x + v.y*v.y + v.z*v.z + v.w*v.w;
            }
            spart[tid] = make_float2(s, q);
        }
        __syncthreads();
        if (tid < 81) {
            float2 p0 = spart[tid*4], p1 = spart[tid*4+1], p2 = spart[tid*4+2], p3 = spart[tid*4+3];
            float s = p0.x+p1.x+p2.x+p3.x, q = p0.y+p1.y+p2.y+p3.y;
            float m = s * (1.f/192.f);
            float var = q * (1.f/192.f) - m*m;
            ssum[tid] = m; ssq[tid] = rsqrtf(var + 1e-5f);
        }
        __syncthreads();
        for (int e = tid; e < 15552; e += 512) {
            int n = e / 192, j = e - n*192;
            float v = vf[n*192 + j];
            v = (v - ssum[n]) * ssq[n] * g_in[j] + be_in[j] + pos[n*192 + j];
            hb[HBI(n, j)] = f2bf(v);
        }
        __syncthreads();
    }

    for (int t = 0; t < NSTEPS; t++) {
        // ===== Phase A: [A|B] = h @ Wm1comb : 24 col-tiles, 3 per wave =====
        for (int c = 0; c < 3; c++) {
            int ct = wave*3 + c;
            bf16x8 wbc[6];
#pragma unroll
            for (int ks = 0; ks < 6; ks++)
                wbc[ks] = wfragN(Wm1b, ct, 6, ks, lane);
            int col = ct*16 + l15;
            float addb = (col >= 192) ? bm1s[col - 192] : 0.f;
#pragma unroll
            for (int rt = 0; rt < 6; rt++) {
                f32x4 acc = {0.f, 0.f, 0.f, 0.f};
#pragma unroll
                for (int ks = 0; ks < 6; ks++)
                    acc = __builtin_amdgcn_mfma_f32_16x16x32_bf16(ldsfrag(hb, rt, ks, lane), wbc[ks], acc, 0, 0, 0);
#pragma unroll
                for (int i2 = 0; i2 < 4; i2++) {
                    int row = rt*16 + q4 + i2;
                    if (row < 81) AB[ABI(row, col)] = f2bf(acc[i2] + addb);
                }
            }
        }
        __syncthreads();   // SYNC_A

        // ===== Phase B: Rb[d] = sum_{s in nbr(d)} relu(A[s] + B[d]) =====
        for (int it = 0; it < 4; it++) {
            int e = tid + 512*it;
            if (e < 1944) {
                int d = e / 24, j8 = e - d*24;
                int j0 = j8 * 8;
                float bsum[8], r8[8] = {0,0,0,0,0,0,0,0};
                us8 bu = *(const us8*)&AB[ABI(d, 192 + j0)];
#pragma unroll
                for (int i = 0; i < 8; i++) bsum[i] = bf2f(bu[i]);
                int rr = d / 9, cc = d - rr*9;
                int rb0 = (rr/3)*3, cb0 = (cc/3)*3;
#pragma unroll
                for (int c2 = 0; c2 < 9; c2++) {
                    if (c2 == cc) continue;
                    us8 au = *(const us8*)&AB[ABI(rr*9 + c2, j0)];
#pragma unroll
                    for (int i = 0; i < 8; i++) r8[i] += fmaxf(bf2f(au[i]) + bsum[i], 0.f);
                }
#pragma unroll
                for (int r2 = 0; r2 < 9; r2++) {
                    if (r2 == rr) continue;
                    us8 au = *(const us8*)&AB[ABI(r2*9 + cc, j0)];
#pragma unroll
                    for (int i = 0; i < 8; i++) r8[i] += fmaxf(bf2f(au[i]) + bsum[i], 0.f);
                }
#pragma unroll
                for (int r2 = 0; r2 < 3; r2++) {
                    int rrr = rb0 + r2;
                    if (rrr == rr) continue;
#pragma unroll
                    for (int c2 = 0; c2 < 3; c2++) {
                        int ccc = cb0 + c2;
                        if (ccc == cc) continue;
                        us8 au = *(const us8*)&AB[ABI(rrr*9 + ccc, j0)];
#pragma unroll
                        for (int i = 0; i < 8; i++) r8[i] += fmaxf(bf2f(au[i]) + bsum[i], 0.f);
                    }
                }
                us8 w;
#pragma unroll
                for (int i = 0; i < 8; i++) w[i] = f2bf(r8[i]);
                *(us8*)&Rb[HBI(d, j0)] = w;
            }
        }
        __syncthreads();   // SYNC_B  (AB dead; hcf overlays it)

        // ===== Phase C part 1: ct = wave (0..7), BOTH row-halves =====
        // weights loaded once per ks, shared across 6 row-tiles (acc in AGPRs)
        {
            int ct = wave;
            int col = ct*16 + l15;
            f32x4 ar[6] = {}, az[6] = {};
#pragma unroll 3
            for (int ks = 0; ks < 12; ks++) {
                bf16x8 wfr = wfragN(Wr, ct, 12, ks, lane);
                bf16x8 wfz = wfragN(Wz, ct, 12, ks, lane);
#pragma unroll
                for (int rt = 0; rt < 6; rt++) {
                    bf16x8 af = (ks < 6) ? ldsfrag(Rb, rt, ks, lane)
                                         : ldsfrag(hb, rt, ks - 6, lane);
                    ar[rt] = __builtin_amdgcn_mfma_f32_16x16x32_bf16(af, wfr, ar[rt], 0,0,0);
                    az[rt] = __builtin_amdgcn_mfma_f32_16x16x32_bf16(af, wfz, az[rt], 0,0,0);
                }
            }
            f32x4 ani[6] = {}, anh[6] = {};
#pragma unroll 3
            for (int ks = 0; ks < 6; ks++) {
                bf16x8 wni = wfragN(Wni, ct, 6, ks, lane);
                bf16x8 wnh = wfragN(Wnh, ct, 6, ks, lane);
#pragma unroll
                for (int rt = 0; rt < 6; rt++) {
                    ani[rt] = __builtin_amdgcn_mfma_f32_16x16x32_bf16(ldsfrag(Rb, rt, ks, lane), wni, ani[rt], 0,0,0);
                    anh[rt] = __builtin_amdgcn_mfma_f32_16x16x32_bf16(ldsfrag(hb, rt, ks, lane), wnh, anh[rt], 0,0,0);
                }
            }
            float br  = biasfs[col]       + bhhs[col];
            float bz  = biasfs[col + 192] + bhhs[col + 192];
            float bni = biasfs[col + 384];
            float bnh = bhhs[col + 384];
#pragma unroll
            for (int rt = 0; rt < 6; rt++) {
#pragma unroll
                for (int i2 = 0; i2 < 4; i2++) {
                    int row = rt*16 + q4 + i2;
                    if (row < 81) {
                        float hv = bf2f(hb[HBI(row, col)]);
                        float rg = 1.f/(1.f + __expf(-(ar[rt][i2] + br)));
                        float zg = 1.f/(1.f + __expf(-(az[rt][i2] + bz)));
                        float e2 = __expf(2.f*(ani[rt][i2] + bni + rg*(anh[rt][i2] + bnh)));
                        float ng = 1.f - 2.f/(e2 + 1.f);
                        hcf[HFI(row, col)] = (1.f - zg)*ng + zg*hv;
                    }
                }
            }
        }
        // ===== Phase C part 2: odd unit, ct = 8 + (wave>>1), rh = wave&1 ====
        {
            int ct = 8 + (wave >> 1), rh = wave & 1;
            int col = ct*16 + l15;
            f32x4 ar[3] = {}, az[3] = {};
#pragma unroll 3
            for (int ks = 0; ks < 12; ks++) {
                bf16x8 wfr = wfragN(Wr, ct, 12, ks, lane);
                bf16x8 wfz = wfragN(Wz, ct, 12, ks, lane);
#pragma unroll
                for (int r3 = 0; r3 < 3; r3++) {
                    int rt = rh*3 + r3;
                    bf16x8 af = (ks < 6) ? ldsfrag(Rb, rt, ks, lane)
                                         : ldsfrag(hb, rt, ks - 6, lane);
                    ar[r3] = __builtin_amdgcn_mfma_f32_16x16x32_bf16(af, wfr, ar[r3], 0,0,0);
                    az[r3] = __builtin_amdgcn_mfma_f32_16x16x32_bf16(af, wfz, az[r3], 0,0,0);
                }
            }
            f32x4 ani[3] = {}, anh[3] = {};
#pragma unroll 3
            for (int ks = 0; ks < 6; ks++) {
                bf16x8 wni = wfragN(Wni, ct, 6, ks, lane);
                bf16x8 wnh = wfragN(Wnh, ct, 6, ks, lane);
#pragma unroll
                for (int r3 = 0; r3 < 3; r3++) {
                    int rt = rh*3 + r3;
                    ani[r3] = __builtin_amdgcn_mfma_f32_16x16x32_bf16(ldsfrag(Rb, rt, ks, lane), wni, ani[r3], 0,0,0);
                    anh[r3] = __builtin_amdgcn_mfma_f32_16x16x32_bf16(ldsfrag(hb, rt, ks, lane), wnh, anh[r3], 0,0,0);
                }
            }
            float br  = biasfs[col]       + bhhs[col];
            float bz  = biasfs[col + 192] + bhhs[col + 192];
            float bni = biasfs[col + 384];
            float bnh = bhhs[col + 384];
#pragma unroll
            for (int r3 = 0; r3 < 3; r3++) {
#pragma unroll
                for (int i2 = 0; i2 < 4; i2++) {
                    int row = (rh*3 + r3)*16 + q4 + i2;
                    if (row < 81) {
                        float hv = bf2f(hb[HBI(row, col)]);
                        float rg = 1.f/(1.f + __expf(-(ar[r3][i2] + br)));
                        float zg = 1.f/(1.f + __expf(-(az[r3][i2] + bz)));
                        float e2 = __expf(2.f*(ani[r3][i2] + bni + rg*(anh[r3][i2] + bnh)));
                        float ng = 1.f - 2.f/(e2 + 1.f);
                        hcf[HFI(row, col)] = (1.f - zg)*ng + zg*hv;
                    }
                }
            }
        }
        __syncthreads();   // SYNC_C

        // ===== LN stats (324-thread partial pass over hcf) =====
        if (tid < 324) {
            int row = tid >> 2, part = tid & 3;
            float s = 0.f, q = 0.f;
#pragma unroll
            for (int i = 0; i < 12; i++) {
                float4 v = *(float4*)&hcf[HFI(row, part*48 + i*4)];
                s += v.x + v.y + v.z + v.w;
                q += v.x*v.x + v.y*v.y + v.z*v.z + v.w*v.w;
            }
            spart[tid] = make_float2(s, q);
        }
        __syncthreads();   // SYNC_S1
        if (tid < 81) {
            float2 p0 = spart[tid*4], p1 = spart[tid*4+1], p2 = spart[tid*4+2], p3 = spart[tid*4+3];
            float s = p0.x+p1.x+p2.x+p3.x, q = p0.y+p1.y+p2.y+p3.y;
            float m = s * (1.f/192.f);
            float var = q * (1.f/192.f) - m*m;
            ssum[tid] = m; ssq[tid] = rsqrtf(var + 1e-5f);
        }
        __syncthreads();   // SYNC_S2

        // ===== Phase D: LayerNorm -> new h (bf16) =====
        for (int e = tid; e < 15552; e += 512) {
            int n = e / 192, j = e - n*192;
            float hc = hcf[HFI(n, j)];
            float hn2 = (hc - ssum[n]) * ssq[n] * gns[j] + bens[j];
            hb[HBI(n, j)] = f2bf(hn2);
        }
        __syncthreads();   // SYNC_D

        // ===== Phase E: logits = h @ W_out + b_out (waves 0-5) =====
        if (wave < 6) {
            int rt = wave;
            f32x4 acc = {0.f, 0.f, 0.f, 0.f};
#pragma unroll
            for (int ks = 0; ks < 6; ks++) {
                bf16x8 ha = ldsfrag(hb, rt, ks, lane);
                acc = __builtin_amdgcn_mfma_f32_16x16x32_bf16(ha, wfragN(Woutb, 0, 6, ks, lane), acc, 0,0,0);
            }
            if (l15 < 9) {
                float bo = b_out[l15];
#pragma unroll
                for (int i2 = 0; i2 < 4; i2++) {
                    int row = rt*16 + q4 + i2;
                    if (row < 81) {
                        float v = acc[i2] + bo;
                        out_all[((size_t)t*NNODES + (size_t)g*81 + row)*9 + l15] = v;
                        if (t == NSTEPS-1)
                            out_last[((size_t)g*81 + row)*9 + l15] = v;
                    }
                }
            }
        }
    }
}

// ---------------------------------------------------------------------------
extern "C" void kernel_launch(void* const* d_in, const int* in_sizes, int n_in,
                              void* d_out, int out_size, void* d_ws, size_t ws_size,
                              hipStream_t stream) {
    const float* x     = (const float*)d_in[0];
    const float* W_in  = (const float*)d_in[2];
    const float* b_in  = (const float*)d_in[3];
    const float* g_in  = (const float*)d_in[4];
    const float* be_in = (const float*)d_in[5];
    const float* pos   = (const float*)d_in[6];
    const float* W_m1  = (const float*)d_in[7];
    const float* b_m1  = (const float*)d_in[8];
    const float* W_m2  = (const float*)d_in[9];
    const float* b_m2  = (const float*)d_in[10];
    const float* W_ih  = (const float*)d_in[11];
    const float* W_hh  = (const float*)d_in[12];
    const float* b_ih  = (const float*)d_in[13];
    const float* b_hh  = (const float*)d_in[14];
    const float* g_n   = (const float*)d_in[15];
    const float* be_n  = (const float*)d_in[16];
    const float* W_out = (const float*)d_in[17];
    const float* b_out = (const float*)d_in[18];

    char* ws = (char*)d_ws;
    float*    Wfused = (float*)ws;                   // 442368
    ushort_t* Wm1b   = (ushort_t*)(ws + 442368);     // 147456
    ushort_t* Wr     = (ushort_t*)(ws + 589824);     // 147456
    ushort_t* Wz     = (ushort_t*)(ws + 737280);     // 147456
    ushort_t* Wni    = (ushort_t*)(ws + 884736);     // 73728
    ushort_t* Wnh    = (ushort_t*)(ws + 958464);     // 73728
    ushort_t* Woutb  = (ushort_t*)(ws + 1032192);    // 6144
    float*    bias_f = (float*)(ws + 1038336);       // 2304

    float* out_last = (float*)d_out;                 // (5184, 9)
    float* out_all  = (float*)d_out + NNODES*9;      // (16, 5184, 9)

    // Wfused = W_m2 @ W_ih^T   (192 x 576, fp32)
    k_gemm<true><<<dim3(3, 9), 256, 0, stream>>>(W_m2, W_ih, nullptr, 0.f, Wfused, 576);
    // weight -> bf16 fragment layouts + fused bias
    k_prep<<<(298560 + 255)/256, 256, 0, stream>>>(W_m1, Wfused, W_hh, W_out, W_ih, b_m2, b_ih,
                                                   Wm1b, Wr, Wz, Wni, Wnh, Woutb, bias_f);

    const int LDS_BYTES = 134568;
    hipFuncSetAttribute(reinterpret_cast<const void*>(k_main),
                        hipFuncAttributeMaxDynamicSharedMemorySize, LDS_BYTES);
    k_main<<<64, 512, LDS_BYTES, stream>>>(x, W_in, b_in, g_in, be_in, pos, b_m1, g_n, be_n,
                                           b_hh, b_out, Wm1b, Wr, Wz, Wni, Wnh, Woutb, bias_f,
                                           out_all, out_last);
}